// Round 11
// baseline (332.706 us; speedup 1.0000x reference)
//
#include <hip/hip_runtime.h>

typedef unsigned long long u64;
typedef unsigned short u16;
typedef unsigned u32;

#define PRE   2000
#define POST  300
#define NCLS  5
#define CAP   512            // max dets/clusters per class (input ~400/class)
#define SORTN 2048
#define INF   0x7fffffff
#define MAGIC 0x13579BDFu

// Exact threshold midpoint: fl32(inter/uni) > 0.55f  <=>  inter >= MID*uni (uni>0).
// MID = 0.55f + 2^-25; MID*(24-bit uni) exact in f64 -> bit-exact predicate.
// Validated: absmax == 0.0 in rounds 3-10.
#define MID 0x1.19999A8p-1

// Compile-time unroller: constant indices at IR-gen (before SROA) so register
// arrays scalarize (validated round 9/10).
template <int K> struct IC { static constexpr int v = K; };
template <int N, typename F> __device__ __forceinline__ void unrollN(F&& f) {
    if constexpr (N > 0) { unrollN<N - 1>(f); f(IC<N - 1>{}); }
}

__device__ __forceinline__ float rdlanef(float v, int l) {
    return __int_as_float(__builtin_amdgcn_readlane(__float_as_int(v), l));
}

__device__ __forceinline__ u32 aload_acq(u32* p) {
    return __hip_atomic_load(p, __ATOMIC_ACQUIRE, __HIP_MEMORY_SCOPE_AGENT);
}
__device__ __forceinline__ u32 aload_rlx(u32* p) {
    return __hip_atomic_load(p, __ATOMIC_RELAXED, __HIP_MEMORY_SCOPE_AGENT);
}

// exact reference IoU>0.55 predicate vs a mean box (a1 = area of det box)
__device__ __forceinline__ bool iou_pred(float bx0, float bx1, float bx2, float bx3,
                                         float a1, float m0, float m1, float m2, float m3,
                                         float a2) {
    const float ltx = fmaxf(bx0, m0), lty = fmaxf(bx1, m1);
    const float rbx = fminf(bx2, m2), rby = fminf(bx3, m3);
    const float wd = fmaxf(rbx - ltx, 0.f), hg = fmaxf(rby - lty, 0.f);
    const float inter = wd * hg;
    const float uni = (a1 + a2) - inter;
    return (uni > 0.f) && ((double)inter >= MID * (double)uni);
}

// ---------- fused kernel: matrix (160 blocks) -> per-class barrier -> scan (5 blocks)
// with 155 heater blocks keeping DVFS clocks up during the serial scan.
__global__ __launch_bounds__(64, 1) void wbf_main(const float* __restrict__ x,
                                                  u64* __restrict__ M,
                                                  u32* __restrict__ ctrl,
                                                  float* __restrict__ recs,
                                                  int* __restrict__ cnts) {
#pragma clang fp contract(off)
    __shared__ u64   s_mtx[CAP * 8];     // 32 KB (scan phase)
    __shared__ u16   s_list[CAP];
    __shared__ float s_dov[16][12];      // dirty overflow

    const int lane = threadIdx.x;
    const int cls = blockIdx.x >> 5;
    const int slice = blockIdx.x & 31;
    const float mycls = (float)cls;
    // ctrl[]: [0..4] class arrival ctrs, [16] done ctr, [32] init flag, [48] dummy

    // ---- init handshake: block 0 zeroes counters, releases MAGIC flag ----
    if (blockIdx.x == 0) {
        if (lane == 0) {
            for (int i = 0; i < NCLS; ++i)
                __hip_atomic_store(&ctrl[i], 0u, __ATOMIC_RELAXED, __HIP_MEMORY_SCOPE_AGENT);
            __hip_atomic_store(&ctrl[16], 0u, __ATOMIC_RELAXED, __HIP_MEMORY_SCOPE_AGENT);
            __hip_atomic_store(&ctrl[32], MAGIC, __ATOMIC_RELEASE, __HIP_MEMORY_SCOPE_AGENT);
        }
    } else {
        if (lane == 0) { while (aload_acq(&ctrl[32]) != MAGIC) {} }
    }
    __syncthreads();

    // ---- phase A: compaction + matrix slice (all 160 blocks) ----
    int myn = 0;
    for (int t0 = 0; t0 < PRE; t0 += 64) {
        const int t = t0 + lane;
        const bool p = (t < PRE) && (x[t * 6 + 5] == mycls);
        const u64 mask = __ballot(p);
        const int pos = myn + __popcll(mask & (((u64)1 << lane) - 1));
        if (p && pos < CAP) s_list[pos] = (u16)t;
        myn += __popcll(mask);
    }
    if (myn > CAP) myn = CAP;

    {   // column solo means (lane-distributed)
        float qc0[8], qc1[8], qc2[8], qc3[8], ac[8];
        unrollN<8>([&](auto k_) {
            constexpr int K = decltype(k_)::v;
            const int c = K * 64 + lane;
            qc0[K] = 0.f; qc1[K] = 0.f; qc2[K] = 0.f; qc3[K] = 0.f; ac[K] = 0.f;
            if (c < myn) {
                const int g = s_list[c];
                const float* p = x + g * 6;
                const float b0 = p[0], b1 = p[1], b2 = p[2], b3 = p[3], sc = p[4];
                qc0[K] = (sc * b0) / sc; qc1[K] = (sc * b1) / sc;
                qc2[K] = (sc * b2) / sc; qc3[K] = (sc * b3) / sc;
                ac[K] = (qc2[K] - qc0[K]) * (qc3[K] - qc1[K]);
            }
        });
        const int rlo = slice * 16;
        const int rhi = (rlo + 16 < myn) ? rlo + 16 : myn;
        for (int r = rlo; r < rhi; ++r) {
            const int g = s_list[r];
            const float* p = x + g * 6;
            const float bx0 = p[0], bx1 = p[1], bx2 = p[2], bx3 = p[3];
            const float a1 = (bx2 - bx0) * (bx3 - bx1);
            unrollN<8>([&](auto w_) {
                constexpr int W = decltype(w_)::v;
                const int c = W * 64 + lane;
                const bool pred = (c < r) &&
                    iou_pred(bx0, bx1, bx2, bx3, a1, qc0[W], qc1[W], qc2[W], qc3[W], ac[W]);
                const u64 bits = __ballot(pred);
                if (lane == 0) M[((size_t)(cls * CAP + r)) * 8 + W] = bits;
            });
        }
    }
    __threadfence();   // device-scope release of matrix rows
    if (lane == 0) __hip_atomic_fetch_add(&ctrl[cls], 1u, __ATOMIC_RELAXED, __HIP_MEMORY_SCOPE_AGENT);

    if (slice != 0) {
        // ---- heater: sustained VALU activity until all 5 scans complete ----
        float f0 = 1.0f, f1 = 1.5f;
        const float a = 1.0000001f, b = 1e-7f;
        while (aload_rlx(&ctrl[16]) < (u32)NCLS) {
            #pragma unroll 32
            for (int it = 0; it < 256; ++it) { f0 = f0 * a + b; f1 = f1 * a + b; }
        }
        if (f0 == 0.123456f && lane == 0) ((float*)&ctrl[48])[0] = f1;  // keep FMAs live
        return;
    }

    // ---- scan block: wait for this class's 32 matrix slices ----
    if (lane == 0) { while (aload_acq(&ctrl[cls]) < 32u) {} }
    __syncthreads();

    // stage matrix rows to LDS
    {
        const ulonglong2* Mg = (const ulonglong2*)(M + (size_t)cls * CAP * 8);
        ulonglong2* Ml = (ulonglong2*)s_mtx;
        for (int it = lane; it < CAP * 4; it += 64) Ml[it] = Mg[it];
    }

    // preload det fields, rank-indexed lane-distributed
    float rb0[8], rb1[8], rb2[8], rb3[8], rsc[8];
    int   rg[8];
    unrollN<8>([&](auto k_) {
        constexpr int K = decltype(k_)::v;
        const int rr = K * 64 + lane;
        rb0[K] = 0.f; rb1[K] = 0.f; rb2[K] = 0.f; rb3[K] = 0.f; rsc[K] = 1.f; rg[K] = 0;
        if (rr < myn) {
            const int g = s_list[rr];
            const float* p = x + g * 6;
            const float2 f01 = *(const float2*)p;
            const float2 f23 = *(const float2*)(p + 2);
            rb0[K] = f01.x; rb1[K] = f01.y; rb2[K] = f23.x; rb3[K] = f23.y;
            rsc[K] = p[4]; rg[K] = g;
        }
    });

    // serial scan state
    u64 alive[8];
    unrollN<8>([&](auto k_) { alive[decltype(k_)::v] = 0ull; });
    float dm0 = 0.f, dm1 = 0.f, dm2 = 0.f, dm3 = 0.f, da = 0.f;
    float e0 = 0.f, e1 = 0.f, e2 = 0.f, e3 = 0.f, ess = 0.f;
    int   drk = INF, dgi = 0, dct = 0;
    int dirtyCnt = 0;

    ulonglong2 pfa, pfb, pfc, pfd;
    {
        const ulonglong2* rp = (const ulonglong2*)&s_mtx[0];
        pfa = rp[0]; pfb = rp[1]; pfc = rp[2]; pfd = rp[3];
    }

    unrollN<8>([&](auto k_) {
        constexpr int K = decltype(k_)::v;
        if (K * 64 < myn) {
            const int iend = (myn - K * 64 < 64) ? (myn - K * 64) : 64;
            for (int i = 0; i < iend; ++i) {
                const int r = K * 64 + i;
                u64 row[8];
                row[0] = pfa.x; row[1] = pfa.y; row[2] = pfb.x; row[3] = pfb.y;
                row[4] = pfc.x; row[5] = pfc.y; row[6] = pfd.x; row[7] = pfd.y;
                {
                    const int rn = (r + 1 < myn) ? r + 1 : r;
                    const ulonglong2* rp = (const ulonglong2*)&s_mtx[(size_t)rn * 8];
                    pfa = rp[0]; pfb = rp[1]; pfc = rp[2]; pfd = rp[3];
                }
                const float bx0 = rdlanef(rb0[K], i);
                const float bx1 = rdlanef(rb1[K], i);
                const float bx2 = rdlanef(rb2[K], i);
                const float bx3 = rdlanef(rb3[K], i);
                const float sc  = rdlanef(rsc[K], i);
                const float a1 = (bx2 - bx0) * (bx3 - bx1);

                int rank_c = INF;
                unrollN<8>([&](auto w_) {
                    constexpr int W = decltype(w_)::v;
                    const u64 m = row[W] & alive[W];
                    if (rank_c == INF && m) rank_c = W * 64 + (int)__builtin_ctzll(m);
                });

                int rank_d = INF, wl = -1;
                if (dirtyCnt > 0) {
                    const bool v = lane < dirtyCnt;
                    const bool p = v && iou_pred(bx0, bx1, bx2, bx3, a1,
                                                 dm0, dm1, dm2, dm3, da);
                    u64 mk = __ballot(p);
                    while (mk) {
                        const int l = (int)__builtin_ctzll(mk);
                        mk &= mk - 1;
                        const int rk = __builtin_amdgcn_readlane(drk, l);
                        if (rk < rank_d) { rank_d = rk; wl = l; }
                    }
                    if (dirtyCnt > 64) {
                        const int no = (dirtyCnt - 64 < 16) ? dirtyCnt - 64 : 16;
                        for (int o = 0; o < no; ++o) {
                            const float m0 = s_dov[o][0], m1 = s_dov[o][1];
                            const float m2 = s_dov[o][2], m3 = s_dov[o][3];
                            const float ar = (m2 - m0) * (m3 - m1);
                            if (iou_pred(bx0, bx1, bx2, bx3, a1, m0, m1, m2, m3, ar)) {
                                const int rk = ((const int*)s_dov[o])[9];
                                if (rk < rank_d) { rank_d = rk; wl = 64 + o; }
                            }
                        }
                    }
                }

                if (rank_c == INF && rank_d == INF) {
                    alive[K] |= 1ull << i;      // CREATE: one bit
                } else if (rank_c < rank_d) {
                    // MERGE into clean cluster rc: goes dirty
                    const int rc = rank_c;
                    unrollN<8>([&](auto w_) {
                        constexpr int W = decltype(w_)::v;
                        if ((rc >> 6) == W) alive[W] &= ~(1ull << (rc & 63));
                    });
                    float cb0 = 0.f, cb1 = 0.f, cb2 = 0.f, cb3 = 0.f, csc = 1.f;
                    int cgi = 0;
                    unrollN<8>([&](auto w_) {
                        constexpr int W = decltype(w_)::v;
                        if ((rc >> 6) == W) {
                            const int l = rc & 63;
                            cb0 = rdlanef(rb0[W], l); cb1 = rdlanef(rb1[W], l);
                            cb2 = rdlanef(rb2[W], l); cb3 = rdlanef(rb3[W], l);
                            csc = rdlanef(rsc[W], l);
                            cgi = __builtin_amdgcn_readlane(rg[W], l);
                        }
                    });
                    const float ns0 = (csc * cb0) + sc * bx0;
                    const float ns1 = (csc * cb1) + sc * bx1;
                    const float ns2 = (csc * cb2) + sc * bx2;
                    const float ns3 = (csc * cb3) + sc * bx3;
                    const float nss = csc + sc;
                    const float nm0 = ns0 / nss, nm1 = ns1 / nss;
                    const float nm2 = ns2 / nss, nm3 = ns3 / nss;
                    if (dirtyCnt < 64) {
                        if (lane == dirtyCnt) {
                            dm0 = nm0; dm1 = nm1; dm2 = nm2; dm3 = nm3;
                            da = (nm2 - nm0) * (nm3 - nm1);
                            e0 = ns0; e1 = ns1; e2 = ns2; e3 = ns3; ess = nss;
                            drk = rc; dgi = cgi; dct = 2;
                        }
                    } else if (dirtyCnt - 64 < 16) {
                        const int o = dirtyCnt - 64;
                        if (lane == 0) {
                            s_dov[o][0] = nm0; s_dov[o][1] = nm1;
                            s_dov[o][2] = nm2; s_dov[o][3] = nm3;
                            s_dov[o][4] = ns0; s_dov[o][5] = ns1;
                            s_dov[o][6] = ns2; s_dov[o][7] = ns3;
                            s_dov[o][8] = nss;
                            ((int*)s_dov[o])[9] = rc; ((int*)s_dov[o])[10] = cgi;
                            ((int*)s_dov[o])[11] = 2;
                        }
                    }
                    dirtyCnt++;
                } else {
                    // MERGE into existing dirty cluster
                    if (wl < 64) {
                        if (lane == wl) {
                            e0 = e0 + sc * bx0; e1 = e1 + sc * bx1;
                            e2 = e2 + sc * bx2; e3 = e3 + sc * bx3;
                            ess = ess + sc; dct++;
                            dm0 = e0 / ess; dm1 = e1 / ess;
                            dm2 = e2 / ess; dm3 = e3 / ess;
                            da = (dm2 - dm0) * (dm3 - dm1);
                        }
                    } else {
                        const int o = wl - 64;
                        const float f0 = s_dov[o][4] + sc * bx0;
                        const float f1 = s_dov[o][5] + sc * bx1;
                        const float f2 = s_dov[o][6] + sc * bx2;
                        const float f3 = s_dov[o][7] + sc * bx3;
                        const float fs = s_dov[o][8] + sc;
                        if (lane == 0) {
                            s_dov[o][0] = f0 / fs; s_dov[o][1] = f1 / fs;
                            s_dov[o][2] = f2 / fs; s_dov[o][3] = f3 / fs;
                            s_dov[o][4] = f0; s_dov[o][5] = f1;
                            s_dov[o][6] = f2; s_dov[o][7] = f3;
                            s_dov[o][8] = fs;
                            ((int*)s_dov[o])[11] += 1;
                        }
                    }
                }
            }
        }
    });

    // emit compacted records: clean (solo mean, score=sc) then dirty
    int wo = 0;
    unrollN<8>([&](auto k_) {
        constexpr int K = decltype(k_)::v;
        const u64 am = alive[K];
        const bool pred = (am >> lane) & 1;
        if (pred) {
            const int pos = wo + (int)__popcll(am & (((u64)1 << lane) - 1));
            const float sc = rsc[K];
            float* rec = recs + (size_t)(cls * CAP + pos) * 8;
            rec[0] = (sc * rb0[K]) / sc; rec[1] = (sc * rb1[K]) / sc;
            rec[2] = (sc * rb2[K]) / sc; rec[3] = (sc * rb3[K]) / sc;
            rec[4] = sc;
            ((int*)rec)[5] = rg[K];
        }
        wo += (int)__popcll(am);
    });
    const int nreg = (dirtyCnt < 64) ? dirtyCnt : 64;
    if (lane < nreg) {
        float* rec = recs + (size_t)(cls * CAP + wo + lane) * 8;
        rec[0] = dm0; rec[1] = dm1; rec[2] = dm2; rec[3] = dm3;
        rec[4] = ess / (float)dct;
        ((int*)rec)[5] = dgi;
    }
    const int nov = (dirtyCnt > 64) ? ((dirtyCnt - 64 < 16) ? dirtyCnt - 64 : 16) : 0;
    for (int o = 0; o < nov; ++o) {
        if (lane == 0) {
            float* rec = recs + (size_t)(cls * CAP + wo + nreg + o) * 8;
            rec[0] = s_dov[o][0]; rec[1] = s_dov[o][1];
            rec[2] = s_dov[o][2]; rec[3] = s_dov[o][3];
            rec[4] = s_dov[o][8] / (float)(((const int*)s_dov[o])[11]);
            ((int*)rec)[5] = ((const int*)s_dov[o])[10];
        }
    }
    if (lane == 0) cnts[cls] = wo + nreg + nov;
    __threadfence();
    if (lane == 0) __hip_atomic_fetch_add(&ctrl[16], 1u, __ATOMIC_RELEASE, __HIP_MEMORY_SCOPE_AGENT);
}

// ---------- sort kernel: compact + sort by (score desc, first_g asc), emit top-300 ----
__global__ __launch_bounds__(512) void wbf_sort(const float* __restrict__ recs,
                                                const int* __restrict__ cnts,
                                                float* __restrict__ out) {
    __shared__ u64 s_keys[SORTN];
    const int tid = threadIdx.x;

    int c[NCLS], off[NCLS];
    int n = 0;
    #pragma unroll
    for (int w = 0; w < NCLS; ++w) { c[w] = cnts[w]; off[w] = n; n += c[w]; }
    if (n > PRE) n = PRE;

    #pragma unroll
    for (int w = 0; w < NCLS; ++w) {
        const int cw = c[w], ow = off[w];
        for (int j = tid; j < cw; j += 512) {
            const float* r = recs + (size_t)(w * CAP + j) * 8;
            const unsigned sb = __float_as_uint(r[4]);
            const int g = ((const int*)r)[5];
            const int id = w * CAP + j;
            u64 key = ((u64)sb << 32) | ((u64)(unsigned)(0xFFFF - g) << 16) | (u64)id;
            s_keys[ow + j] = ~key;
        }
    }
    for (int i = n + tid; i < SORTN; i += 512) s_keys[i] = ~0ull;
    __syncthreads();

    for (int kk = 2; kk <= SORTN; kk <<= 1) {
        for (int jj = kk >> 1; jj > 0; jj >>= 1) {
            for (int i = tid; i < SORTN; i += 512) {
                const int ixj = i ^ jj;
                if (ixj > i) {
                    const u64 a = s_keys[i], b = s_keys[ixj];
                    const bool up = ((i & kk) == 0);
                    if ((a > b) == up) { s_keys[i] = b; s_keys[ixj] = a; }
                }
            }
            __syncthreads();
        }
    }

    for (int r = tid; r < POST; r += 512) {
        float* o = out + r * 6;
        if (r < n) {
            const u64 key = ~s_keys[r];
            const int id = (int)(key & 0xFFFFull);
            const float* rec = recs + (size_t)id * 8;
            o[0] = rec[0]; o[1] = rec[1]; o[2] = rec[2]; o[3] = rec[3];
            o[4] = __uint_as_float((unsigned)(key >> 32));
            o[5] = (float)(id >> 9);
        } else {
            o[0] = 0.f; o[1] = 0.f; o[2] = 0.f; o[3] = 0.f; o[4] = 0.f; o[5] = 0.f;
        }
    }
}

extern "C" void kernel_launch(void* const* d_in, const int* in_sizes, int n_in,
                              void* d_out, int out_size, void* d_ws, size_t ws_size,
                              hipStream_t stream) {
    const float* x = (const float*)d_in[0];
    float* out = (float*)d_out;
    // ws layout: M 160 KB | ctrl 256 B | cnts 256 B | recs 80 KB  (~241 KB total)
    u64* M    = (u64*)d_ws;
    u32* ctrl = (u32*)((char*)d_ws + (size_t)NCLS * CAP * 8 * 8);
    int* cnts = (int*)((char*)d_ws + (size_t)NCLS * CAP * 8 * 8 + 256);
    float* recs = (float*)((char*)d_ws + (size_t)NCLS * CAP * 8 * 8 + 512);
    wbf_main<<<NCLS * 32, 64, 0, stream>>>(x, M, ctrl, recs, cnts);
    wbf_sort<<<1, 512, 0, stream>>>(recs, cnts, out);
}

// Round 12
// 254.816 us; speedup vs baseline: 1.3057x; 1.3057x over previous
//
#include <hip/hip_runtime.h>

typedef unsigned long long u64;
typedef unsigned short u16;
typedef unsigned u32;
typedef unsigned char u8;

#define PRE   2000
#define POST  300
#define NCLS  5
#define CAP   512            // max dets/clusters per class (input ~400/class)
#define SORTN 2048
#define INF   0x7fffffff
#define MAGIC 0x13579BDFu

// Exact threshold midpoint: fl32(inter/uni) > 0.55f  <=>  inter >= MID*uni (uni>0).
// MID = 0.55f + 2^-25; MID*(24-bit uni) exact in f64 -> bit-exact predicate.
// Validated: absmax == 0.0 in rounds 3-11.
#define MID 0x1.19999A8p-1

// Compile-time unroller: constant indices at IR-gen (before SROA) so register
// arrays scalarize (validated rounds 9-11).
template <int K> struct IC { static constexpr int v = K; };
template <int N, typename F> __device__ __forceinline__ void unrollN(F&& f) {
    if constexpr (N > 0) { unrollN<N - 1>(f); f(IC<N - 1>{}); }
}

__device__ __forceinline__ float rdlanef(float v, int l) {
    return __int_as_float(__builtin_amdgcn_readlane(__float_as_int(v), l));
}

__device__ __forceinline__ u32 aload_acq(u32* p) {
    return __hip_atomic_load(p, __ATOMIC_ACQUIRE, __HIP_MEMORY_SCOPE_AGENT);
}

// exact reference IoU>0.55 predicate vs a mean box (a1 = area of det box)
__device__ __forceinline__ bool iou_pred(float bx0, float bx1, float bx2, float bx3,
                                         float a1, float m0, float m1, float m2, float m3,
                                         float a2) {
    const float ltx = fmaxf(bx0, m0), lty = fmaxf(bx1, m1);
    const float rbx = fminf(bx2, m2), rby = fminf(bx3, m3);
    const float wd = fmaxf(rbx - ltx, 0.f), hg = fmaxf(rby - lty, 0.f);
    const float inter = wd * hg;
    const float uni = (a1 + a2) - inter;
    return (uni > 0.f) && ((double)inter >= MID * (double)uni);
}

// ---------- fused: matrix (160 blocks) -> per-class spin barrier -> scan (5 blocks)
__global__ __launch_bounds__(64, 1) void wbf_main(const float* __restrict__ x,
                                                  u64* __restrict__ M,
                                                  u32* __restrict__ ctrl,
                                                  float* __restrict__ recs,
                                                  int* __restrict__ cnts) {
#pragma clang fp contract(off)
    __shared__ u8    s_mtx[CAP * 64];    // 32 KB: matrix rows, byte-sliced per lane
    __shared__ u16   s_list[CAP];
    __shared__ float s_dov[16][12];      // dirty overflow

    const int lane = threadIdx.x;
    const int cls = blockIdx.x >> 5;
    const int slice = blockIdx.x & 31;
    const float mycls = (float)cls;

    // ---- init handshake ----
    if (blockIdx.x == 0) {
        if (lane == 0) {
            for (int i = 0; i < NCLS; ++i)
                __hip_atomic_store(&ctrl[i], 0u, __ATOMIC_RELAXED, __HIP_MEMORY_SCOPE_AGENT);
            __hip_atomic_store(&ctrl[32], MAGIC, __ATOMIC_RELEASE, __HIP_MEMORY_SCOPE_AGENT);
        }
    } else {
        if (lane == 0) { while (aload_acq(&ctrl[32]) != MAGIC) {} }
    }
    __syncthreads();

    // ---- phase A: compaction + matrix slice (all 160 blocks) ----
    int myn = 0;
    for (int t0 = 0; t0 < PRE; t0 += 64) {
        const int t = t0 + lane;
        const bool p = (t < PRE) && (x[t * 6 + 5] == mycls);
        const u64 mask = __ballot(p);
        const int pos = myn + __popcll(mask & (((u64)1 << lane) - 1));
        if (p && pos < CAP) s_list[pos] = (u16)t;
        myn += __popcll(mask);
    }
    if (myn > CAP) myn = CAP;

    {   // column solo means (lane-distributed)
        float qc0[8], qc1[8], qc2[8], qc3[8], ac[8];
        unrollN<8>([&](auto k_) {
            constexpr int K = decltype(k_)::v;
            const int c = K * 64 + lane;
            qc0[K] = 0.f; qc1[K] = 0.f; qc2[K] = 0.f; qc3[K] = 0.f; ac[K] = 0.f;
            if (c < myn) {
                const int g = s_list[c];
                const float* p = x + g * 6;
                const float b0 = p[0], b1 = p[1], b2 = p[2], b3 = p[3], sc = p[4];
                qc0[K] = (sc * b0) / sc; qc1[K] = (sc * b1) / sc;
                qc2[K] = (sc * b2) / sc; qc3[K] = (sc * b3) / sc;
                ac[K] = (qc2[K] - qc0[K]) * (qc3[K] - qc1[K]);
            }
        });
        const int rlo = slice * 16;
        const int rhi = (rlo + 16 < myn) ? rlo + 16 : myn;
        for (int r = rlo; r < rhi; ++r) {
            const int g = s_list[r];
            const float* p = x + g * 6;
            const float bx0 = p[0], bx1 = p[1], bx2 = p[2], bx3 = p[3];
            const float a1 = (bx2 - bx0) * (bx3 - bx1);
            unrollN<8>([&](auto w_) {
                constexpr int W = decltype(w_)::v;
                const int c = W * 64 + lane;
                const bool pred = (c < r) &&
                    iou_pred(bx0, bx1, bx2, bx3, a1, qc0[W], qc1[W], qc2[W], qc3[W], ac[W]);
                const u64 bits = __ballot(pred);
                if (lane == 0) M[((size_t)(cls * CAP + r)) * 8 + W] = bits;
            });
        }
    }
    __threadfence();   // device-scope release of matrix rows
    if (lane == 0) __hip_atomic_fetch_add(&ctrl[cls], 1u, __ATOMIC_RELEASE, __HIP_MEMORY_SCOPE_AGENT);

    if (slice != 0) return;   // no heaters (R11: no effect)

    // ---- scan block: wait for this class's 32 matrix slices ----
    if (lane == 0) { while (aload_acq(&ctrl[cls]) < 32u) {} }
    __syncthreads();

    // stage matrix rows to LDS (byte layout == little-endian u64 layout)
    {
        const ulonglong2* Mg = (const ulonglong2*)(M + (size_t)cls * CAP * 8);
        ulonglong2* Ml = (ulonglong2*)s_mtx;
        for (int it = lane; it < CAP * 4; it += 64) Ml[it] = Mg[it];
    }

    // preload det fields, rank-indexed lane-distributed
    float rb0[8], rb1[8], rb2[8], rb3[8], rsc[8];
    int   rg[8];
    unrollN<8>([&](auto k_) {
        constexpr int K = decltype(k_)::v;
        const int rr = K * 64 + lane;
        rb0[K] = 0.f; rb1[K] = 0.f; rb2[K] = 0.f; rb3[K] = 0.f; rsc[K] = 1.f; rg[K] = 0;
        if (rr < myn) {
            const int g = s_list[rr];
            const float* p = x + g * 6;
            const float2 f01 = *(const float2*)p;
            const float2 f23 = *(const float2*)(p + 2);
            rb0[K] = f01.x; rb1[K] = f01.y; rb2[K] = f23.x; rb3[K] = f23.y;
            rsc[K] = p[4]; rg[K] = g;
        }
    });

    // serial scan state: lane L owns clusters 8L..8L+7 (one byte of the bitset)
    u32 aliveB = 0;
    float dm0 = 0.f, dm1 = 0.f, dm2 = 0.f, dm3 = 0.f, da = 0.f;
    float e0 = 0.f, e1 = 0.f, e2 = 0.f, e3 = 0.f, ess = 0.f;
    int   drk = INF, dgi = 0, dct = 0;
    int dirtyCnt = 0;

    u32 pfByte = (myn > 0) ? (u32)s_mtx[lane] : 0u;   // row 0 bytes

    unrollN<8>([&](auto k_) {
        constexpr int K = decltype(k_)::v;
        if (K * 64 < myn) {
            const int iend = (myn - K * 64 < 64) ? (myn - K * 64) : 64;
            for (int i = 0; i < iend; ++i) {
                const int r = K * 64 + i;
                const u32 rowB = pfByte;
                {   // prefetch next row's byte (1 det of slack hides LDS latency)
                    const int rn = (r + 1 < myn) ? r + 1 : r;
                    pfByte = (u32)s_mtx[rn * 64 + lane];
                }
                const float bx0 = rdlanef(rb0[K], i);
                const float bx1 = rdlanef(rb1[K], i);
                const float bx2 = rdlanef(rb2[K], i);
                const float bx3 = rdlanef(rb3[K], i);
                const float sc  = rdlanef(rsc[K], i);
                const float a1 = (bx2 - bx0) * (bx3 - bx1);

                // clean first-match: lane-parallel bytes -> ballot -> ff1
                const u32 mC = rowB & aliveB;
                const u64 balC = __ballot(mC != 0u);
                int rank_c = INF;
                if (balC) {
                    const int wl = (int)__builtin_ctzll(balC);
                    const u32 byte = (u32)__builtin_amdgcn_readlane((int)mC, wl);
                    rank_c = wl * 8 + (int)__builtin_ctz(byte);
                }

                // dirty matches (means evolve -> evaluate live)
                int rank_d = INF, wl_d = -1;
                if (dirtyCnt > 0) {
                    const bool p = (lane < dirtyCnt) &&
                                   iou_pred(bx0, bx1, bx2, bx3, a1, dm0, dm1, dm2, dm3, da);
                    u64 mk = __ballot(p);
                    while (mk) {
                        const int l = (int)__builtin_ctzll(mk);
                        mk &= mk - 1;
                        const int rk = __builtin_amdgcn_readlane(drk, l);
                        if (rk < rank_d) { rank_d = rk; wl_d = l; }
                    }
                    if (dirtyCnt > 64) {
                        const int no = (dirtyCnt - 64 < 16) ? dirtyCnt - 64 : 16;
                        for (int o = 0; o < no; ++o) {
                            const float m0 = s_dov[o][0], m1 = s_dov[o][1];
                            const float m2 = s_dov[o][2], m3 = s_dov[o][3];
                            const float ar = (m2 - m0) * (m3 - m1);
                            if (iou_pred(bx0, bx1, bx2, bx3, a1, m0, m1, m2, m3, ar)) {
                                const int rk = ((const int*)s_dov[o])[9];
                                if (rk < rank_d) { rank_d = rk; wl_d = 64 + o; }
                            }
                        }
                    }
                }

                if (rank_c == INF && rank_d == INF) {
                    // CREATE (common): branchless one-bit set
                    aliveB |= ((r >> 3) == lane) ? (1u << (r & 7)) : 0u;
                } else if (rank_c < rank_d) {
                    // MERGE into clean cluster rc: remove from clean set, goes dirty
                    const int rc = rank_c;
                    aliveB &= ~(((rc >> 3) == lane) ? (1u << (rc & 7)) : 0u);
                    float cb0 = 0.f, cb1 = 0.f, cb2 = 0.f, cb3 = 0.f, csc = 1.f;
                    int cgi = 0;
                    unrollN<8>([&](auto w_) {
                        constexpr int W = decltype(w_)::v;
                        if ((rc >> 6) == W) {
                            const int l = rc & 63;
                            cb0 = rdlanef(rb0[W], l); cb1 = rdlanef(rb1[W], l);
                            cb2 = rdlanef(rb2[W], l); cb3 = rdlanef(rb3[W], l);
                            csc = rdlanef(rsc[W], l);
                            cgi = __builtin_amdgcn_readlane(rg[W], l);
                        }
                    });
                    // exact ref op order: solo sums fl(csc*cb), += fl(sc*bx), div
                    const float ns0 = (csc * cb0) + sc * bx0;
                    const float ns1 = (csc * cb1) + sc * bx1;
                    const float ns2 = (csc * cb2) + sc * bx2;
                    const float ns3 = (csc * cb3) + sc * bx3;
                    const float nss = csc + sc;
                    const float nm0 = ns0 / nss, nm1 = ns1 / nss;
                    const float nm2 = ns2 / nss, nm3 = ns3 / nss;
                    if (dirtyCnt < 64) {
                        if (lane == dirtyCnt) {
                            dm0 = nm0; dm1 = nm1; dm2 = nm2; dm3 = nm3;
                            da = (nm2 - nm0) * (nm3 - nm1);
                            e0 = ns0; e1 = ns1; e2 = ns2; e3 = ns3; ess = nss;
                            drk = rc; dgi = cgi; dct = 2;
                        }
                    } else if (dirtyCnt - 64 < 16) {
                        const int o = dirtyCnt - 64;
                        if (lane == 0) {
                            s_dov[o][0] = nm0; s_dov[o][1] = nm1;
                            s_dov[o][2] = nm2; s_dov[o][3] = nm3;
                            s_dov[o][4] = ns0; s_dov[o][5] = ns1;
                            s_dov[o][6] = ns2; s_dov[o][7] = ns3;
                            s_dov[o][8] = nss;
                            ((int*)s_dov[o])[9] = rc; ((int*)s_dov[o])[10] = cgi;
                            ((int*)s_dov[o])[11] = 2;
                        }
                    }
                    dirtyCnt++;
                } else {
                    // MERGE into existing dirty cluster
                    if (wl_d < 64) {
                        if (lane == wl_d) {
                            e0 = e0 + sc * bx0; e1 = e1 + sc * bx1;
                            e2 = e2 + sc * bx2; e3 = e3 + sc * bx3;
                            ess = ess + sc; dct++;
                            dm0 = e0 / ess; dm1 = e1 / ess;
                            dm2 = e2 / ess; dm3 = e3 / ess;
                            da = (dm2 - dm0) * (dm3 - dm1);
                        }
                    } else {
                        const int o = wl_d - 64;
                        const float f0 = s_dov[o][4] + sc * bx0;
                        const float f1 = s_dov[o][5] + sc * bx1;
                        const float f2 = s_dov[o][6] + sc * bx2;
                        const float f3 = s_dov[o][7] + sc * bx3;
                        const float fs = s_dov[o][8] + sc;
                        if (lane == 0) {
                            s_dov[o][0] = f0 / fs; s_dov[o][1] = f1 / fs;
                            s_dov[o][2] = f2 / fs; s_dov[o][3] = f3 / fs;
                            s_dov[o][4] = f0; s_dov[o][5] = f1;
                            s_dov[o][6] = f2; s_dov[o][7] = f3;
                            s_dov[o][8] = fs;
                            ((int*)s_dov[o])[11] += 1;
                        }
                    }
                }
            }
        }
    });

    // reconstruct u64 alive words from per-lane bytes (once, off the hot loop)
    u64 alive[8];
    unrollN<8>([&](auto w_) {
        constexpr int W = decltype(w_)::v;
        u64 a = 0;
        #pragma unroll
        for (int b = 0; b < 8; ++b)
            a |= (u64)(u32)__builtin_amdgcn_readlane((int)aliveB, W * 8 + b) << (8 * b);
        alive[W] = a;
    });

    // emit compacted records: clean (solo mean, score=sc) then dirty
    int wo = 0;
    unrollN<8>([&](auto k_) {
        constexpr int K = decltype(k_)::v;
        const u64 am = alive[K];
        const bool pred = (am >> lane) & 1;
        if (pred) {
            const int pos = wo + (int)__popcll(am & (((u64)1 << lane) - 1));
            const float sc = rsc[K];
            float* rec = recs + (size_t)(cls * CAP + pos) * 8;
            rec[0] = (sc * rb0[K]) / sc; rec[1] = (sc * rb1[K]) / sc;
            rec[2] = (sc * rb2[K]) / sc; rec[3] = (sc * rb3[K]) / sc;
            rec[4] = sc;
            ((int*)rec)[5] = rg[K];
        }
        wo += (int)__popcll(am);
    });
    const int nreg = (dirtyCnt < 64) ? dirtyCnt : 64;
    if (lane < nreg) {
        float* rec = recs + (size_t)(cls * CAP + wo + lane) * 8;
        rec[0] = dm0; rec[1] = dm1; rec[2] = dm2; rec[3] = dm3;
        rec[4] = ess / (float)dct;
        ((int*)rec)[5] = dgi;
    }
    const int nov = (dirtyCnt > 64) ? ((dirtyCnt - 64 < 16) ? dirtyCnt - 64 : 16) : 0;
    for (int o = 0; o < nov; ++o) {
        if (lane == 0) {
            float* rec = recs + (size_t)(cls * CAP + wo + nreg + o) * 8;
            rec[0] = s_dov[o][0]; rec[1] = s_dov[o][1];
            rec[2] = s_dov[o][2]; rec[3] = s_dov[o][3];
            rec[4] = s_dov[o][8] / (float)(((const int*)s_dov[o])[11]);
            ((int*)rec)[5] = ((const int*)s_dov[o])[10];
        }
    }
    if (lane == 0) cnts[cls] = wo + nreg + nov;
}

// ---------- sort kernel: compact + sort by (score desc, first_g asc), emit top-300 ----
__global__ __launch_bounds__(512) void wbf_sort(const float* __restrict__ recs,
                                                const int* __restrict__ cnts,
                                                float* __restrict__ out) {
    __shared__ u64 s_keys[SORTN];
    const int tid = threadIdx.x;

    int c[NCLS], off[NCLS];
    int n = 0;
    #pragma unroll
    for (int w = 0; w < NCLS; ++w) { c[w] = cnts[w]; off[w] = n; n += c[w]; }
    if (n > PRE) n = PRE;

    #pragma unroll
    for (int w = 0; w < NCLS; ++w) {
        const int cw = c[w], ow = off[w];
        for (int j = tid; j < cw; j += 512) {
            const float* r = recs + (size_t)(w * CAP + j) * 8;
            const unsigned sb = __float_as_uint(r[4]);
            const int g = ((const int*)r)[5];
            const int id = w * CAP + j;
            u64 key = ((u64)sb << 32) | ((u64)(unsigned)(0xFFFF - g) << 16) | (u64)id;
            s_keys[ow + j] = ~key;
        }
    }
    for (int i = n + tid; i < SORTN; i += 512) s_keys[i] = ~0ull;
    __syncthreads();

    for (int kk = 2; kk <= SORTN; kk <<= 1) {
        for (int jj = kk >> 1; jj > 0; jj >>= 1) {
            for (int i = tid; i < SORTN; i += 512) {
                const int ixj = i ^ jj;
                if (ixj > i) {
                    const u64 a = s_keys[i], b = s_keys[ixj];
                    const bool up = ((i & kk) == 0);
                    if ((a > b) == up) { s_keys[i] = b; s_keys[ixj] = a; }
                }
            }
            __syncthreads();
        }
    }

    for (int r = tid; r < POST; r += 512) {
        float* o = out + r * 6;
        if (r < n) {
            const u64 key = ~s_keys[r];
            const int id = (int)(key & 0xFFFFull);
            const float* rec = recs + (size_t)id * 8;
            o[0] = rec[0]; o[1] = rec[1]; o[2] = rec[2]; o[3] = rec[3];
            o[4] = __uint_as_float((unsigned)(key >> 32));
            o[5] = (float)(id >> 9);
        } else {
            o[0] = 0.f; o[1] = 0.f; o[2] = 0.f; o[3] = 0.f; o[4] = 0.f; o[5] = 0.f;
        }
    }
}

extern "C" void kernel_launch(void* const* d_in, const int* in_sizes, int n_in,
                              void* d_out, int out_size, void* d_ws, size_t ws_size,
                              hipStream_t stream) {
    const float* x = (const float*)d_in[0];
    float* out = (float*)d_out;
    // ws layout: M 160 KB | ctrl 256 B | cnts 256 B | recs 80 KB
    u64* M    = (u64*)d_ws;
    u32* ctrl = (u32*)((char*)d_ws + (size_t)NCLS * CAP * 8 * 8);
    int* cnts = (int*)((char*)d_ws + (size_t)NCLS * CAP * 8 * 8 + 256);
    float* recs = (float*)((char*)d_ws + (size_t)NCLS * CAP * 8 * 8 + 512);
    wbf_main<<<NCLS * 32, 64, 0, stream>>>(x, M, ctrl, recs, cnts);
    wbf_sort<<<1, 512, 0, stream>>>(recs, cnts, out);
}

// Round 13
// 197.034 us; speedup vs baseline: 1.6886x; 1.2933x over previous
//
#include <hip/hip_runtime.h>

typedef unsigned long long u64;
typedef unsigned short u16;
typedef unsigned u32;
typedef unsigned char u8;

#define PRE   2000
#define POST  300
#define NCLS  5
#define CAP   512
#define INF   0x7fffffff
#define MAGIC 0x13579BDFu
#define NBLK  21
#define SORTB 20

// Exact threshold midpoint: fl32(inter/uni) > 0.55f  <=>  inter >= MID*uni (uni>0).
// MID = 0.55f + 2^-25; MID*(24-bit uni) exact in f64 -> bit-exact predicate.
// Validated: absmax == 0.0 in rounds 3-12.
#define MID 0x1.19999A8p-1

template <int K> struct IC { static constexpr int v = K; };
template <int N, typename F> __device__ __forceinline__ void unrollN(F&& f) {
    if constexpr (N > 0) { unrollN<N - 1>(f); f(IC<N - 1>{}); }
}

__device__ __forceinline__ u32 aload_acq(u32* p) {
    return __hip_atomic_load(p, __ATOMIC_ACQUIRE, __HIP_MEMORY_SCOPE_AGENT);
}

__device__ __forceinline__ bool iou_pred(float bx0, float bx1, float bx2, float bx3,
                                         float a1, float m0, float m1, float m2, float m3,
                                         float a2) {
    const float ltx = fmaxf(bx0, m0), lty = fmaxf(bx1, m1);
    const float rbx = fminf(bx2, m2), rby = fminf(bx3, m3);
    const float wd = fmaxf(rbx - ltx, 0.f), hg = fmaxf(rby - lty, 0.f);
    const float inter = wd * hg;
    const float uni = (a1 + a2) - inter;
    return (uni > 0.f) && ((double)inter >= MID * (double)uni);
}

// One kernel: blocks 0-19 matrix (cls=b>>2, 8 slices/block) ; wave0 of b%4==0 scans
// its class after a spin-barrier; block 20 sorts after all 5 scans complete.
__global__ __launch_bounds__(512, 1) void wbf_all(const float* __restrict__ x,
                                                  u64* __restrict__ M,
                                                  u32* __restrict__ ctrl,
                                                  float* __restrict__ recs,
                                                  int* __restrict__ cnts,
                                                  float* __restrict__ out) {
#pragma clang fp contract(off)
    __shared__ __align__(16) char s_buf[50960];
    // matrix/scan roles:
    u8*  s_mtx = (u8*)s_buf;                                 // 32768
    float (*s_det)[8]  = (float (*)[8])(s_buf + 32768);      // 16384
    u16* s_list        = (u16*)(s_buf + 49152);              // 1024
    float (*s_dov)[12] = (float (*)[12])(s_buf + 50176);     // 768
    int* s_myn         = (int*)(s_buf + 50944);

    const int tid  = threadIdx.x;
    const int lane = tid & 63;
    const int wave = tid >> 6;
    const int b    = blockIdx.x;

    // ---- init handshake (ws re-poisoned 0xAA before every launch) ----
    if (b == 0) {
        if (tid == 0) {
            for (int i = 0; i < NCLS; ++i)
                __hip_atomic_store(&ctrl[i], 0u, __ATOMIC_RELAXED, __HIP_MEMORY_SCOPE_AGENT);
            __hip_atomic_store(&ctrl[16], 0u, __ATOMIC_RELAXED, __HIP_MEMORY_SCOPE_AGENT);
            __hip_atomic_store(&ctrl[32], MAGIC, __ATOMIC_RELEASE, __HIP_MEMORY_SCOPE_AGENT);
        }
    } else {
        if (tid == 0) { while (aload_acq(&ctrl[32]) != MAGIC) {} }
    }
    __syncthreads();

    // ================= SORT BLOCK =================
    if (b == SORTB) {
        u64* keys = (u64*)s_buf;             // 2048 x 8 = 16384
        u32* hist = (u32*)(s_buf + 16384);   // 4096 x 4 = 16384
        u64* cand = (u64*)(s_buf + 32768);   // 512 x 8  = 4096
        u32* part = (u32*)(s_buf + 36864);   // 512 x 4  = 2048
        int* scal = (int*)(s_buf + 38912);

        if (tid == 0) { while (aload_acq(&ctrl[16]) < (u32)NCLS) {} }
        __syncthreads();

        int c[NCLS], off[NCLS];
        int n = 0;
        #pragma unroll
        for (int w = 0; w < NCLS; ++w) { c[w] = cnts[w]; off[w] = n; n += c[w]; }
        if (n > 2048) n = 2048;

        #pragma unroll
        for (int w = 0; w < NCLS; ++w) {
            const int cw = c[w], ow = off[w];
            for (int j = tid; j < cw; j += 512) {
                const float* r = recs + (size_t)(w * CAP + j) * 8;
                const unsigned sb = __float_as_uint(r[4]);    // score>0: bits monotone
                const int g = ((const int*)r)[5];
                const int id = w * CAP + j;
                u64 key = ((u64)sb << 32) | ((u64)(unsigned)(0xFFFF - g) << 16) | (u64)id;
                keys[ow + j] = ~key;   // ascending sort of ~key == descending of key
            }
        }
        for (int i = n + tid; i < 2048; i += 512) keys[i] = ~0ull;
        for (int h = tid; h < 4096; h += 512) hist[h] = 0u;
        __syncthreads();

        for (int i = tid; i < n; i += 512)
            atomicAdd(&hist[(u32)(keys[i] >> 52)], 1u);
        __syncthreads();

        const int target = (POST < n) ? POST : n;
        u32 p = 0;
        #pragma unroll
        for (int k = 0; k < 8; ++k) p += hist[tid * 8 + k];
        part[tid] = p;
        __syncthreads();
        for (int o2 = 1; o2 < 512; o2 <<= 1) {
            const u32 v = part[tid];
            const u32 add = (tid >= o2) ? part[tid - o2] : 0u;
            __syncthreads();
            part[tid] = v + add;
            __syncthreads();
        }
        const u32 I = part[tid];
        const u32 E = I - p;
        if ((int)E < target && (int)I >= target) { scal[0] = tid; scal[1] = (int)E; }
        if (tid == 0) scal[2] = 0;
        __syncthreads();
        const int T = scal[0];
        int cum = scal[1];
        int B = T * 8 + 7;
        for (int bb = T * 8; bb < T * 8 + 8; ++bb) {
            const int h = (int)hist[bb];
            if (cum + h >= target) { B = bb; break; }
            cum += h;
        }
        const int candCount = cum + (int)hist[B];

        if (candCount <= 512) {
            for (int i = tid; i < n; i += 512) {
                const u64 kk = keys[i];
                if ((int)(u32)(kk >> 52) <= B) {
                    const int pos = atomicAdd(&scal[2], 1);
                    cand[pos] = kk;
                }
            }
            __syncthreads();
            if (tid >= candCount) cand[tid] = ~0ull;
            __syncthreads();
            for (int kk2 = 2; kk2 <= 512; kk2 <<= 1) {
                for (int jj = kk2 >> 1; jj > 0; jj >>= 1) {
                    const int i = tid, ixj = i ^ jj;
                    if (ixj > i) {
                        const u64 a = cand[i], bb2 = cand[ixj];
                        const bool up = ((i & kk2) == 0);
                        if ((a > bb2) == up) { cand[i] = bb2; cand[ixj] = a; }
                    }
                    __syncthreads();
                }
            }
            if (tid < POST) {
                float* o = out + tid * 6;
                if (tid < target) {
                    const u64 key = ~cand[tid];
                    const int id = (int)(key & 0xFFFFull);
                    const float* rec = recs + (size_t)id * 8;
                    o[0] = rec[0]; o[1] = rec[1]; o[2] = rec[2]; o[3] = rec[3];
                    o[4] = __uint_as_float((unsigned)(key >> 32));
                    o[5] = (float)(id >> 9);
                } else {
                    o[0] = 0.f; o[1] = 0.f; o[2] = 0.f; o[3] = 0.f; o[4] = 0.f; o[5] = 0.f;
                }
            }
        } else {
            // fallback: full 2048 bitonic (proven R12 path)
            for (int kk2 = 2; kk2 <= 2048; kk2 <<= 1) {
                for (int jj = kk2 >> 1; jj > 0; jj >>= 1) {
                    for (int i = tid; i < 2048; i += 512) {
                        const int ixj = i ^ jj;
                        if (ixj > i) {
                            const u64 a = keys[i], bb2 = keys[ixj];
                            const bool up = ((i & kk2) == 0);
                            if ((a > bb2) == up) { keys[i] = bb2; keys[ixj] = a; }
                        }
                    }
                    __syncthreads();
                }
            }
            if (tid < POST) {
                float* o = out + tid * 6;
                if (tid < target) {
                    const u64 key = ~keys[tid];
                    const int id = (int)(key & 0xFFFFull);
                    const float* rec = recs + (size_t)id * 8;
                    o[0] = rec[0]; o[1] = rec[1]; o[2] = rec[2]; o[3] = rec[3];
                    o[4] = __uint_as_float((unsigned)(key >> 32));
                    o[5] = (float)(id >> 9);
                } else {
                    o[0] = 0.f; o[1] = 0.f; o[2] = 0.f; o[3] = 0.f; o[4] = 0.f; o[5] = 0.f;
                }
            }
        }
        return;
    }

    // ================= MATRIX BLOCKS (0..19) =================
    const int cls = b >> 2;
    const float mycls = (float)cls;

    if (wave == 0) {   // wave 0 builds the class det list
        int mn = 0;
        for (int t0 = 0; t0 < PRE; t0 += 64) {
            const int t = t0 + lane;
            const bool pp = (t < PRE) && (x[t * 6 + 5] == mycls);
            const u64 mask = __ballot(pp);
            const int pos = mn + __popcll(mask & (((u64)1 << lane) - 1));
            if (pp && pos < CAP) s_list[pos] = (u16)t;
            mn += __popcll(mask);
        }
        if (mn > CAP) mn = CAP;
        if (lane == 0) *s_myn = mn;
    }
    __syncthreads();
    const int myn = *s_myn;

    {   // each wave computes one 16-row slice of the candidate matrix
        float qc0[8], qc1[8], qc2[8], qc3[8], ac[8];
        unrollN<8>([&](auto k_) {
            constexpr int K = decltype(k_)::v;
            const int c = K * 64 + lane;
            qc0[K] = 0.f; qc1[K] = 0.f; qc2[K] = 0.f; qc3[K] = 0.f; ac[K] = 0.f;
            if (c < myn) {
                const int g = s_list[c];
                const float* p = x + g * 6;
                const float b0 = p[0], b1 = p[1], b2 = p[2], b3 = p[3], sc = p[4];
                qc0[K] = (sc * b0) / sc; qc1[K] = (sc * b1) / sc;
                qc2[K] = (sc * b2) / sc; qc3[K] = (sc * b3) / sc;
                ac[K] = (qc2[K] - qc0[K]) * (qc3[K] - qc1[K]);
            }
        });
        const int slice = (b & 3) * 8 + wave;
        const int rlo = slice * 16;
        const int rhi = (rlo + 16 < myn) ? rlo + 16 : myn;
        for (int r = rlo; r < rhi; ++r) {
            const int g = s_list[r];
            const float* p = x + g * 6;
            const float bx0 = p[0], bx1 = p[1], bx2 = p[2], bx3 = p[3];
            const float a1 = (bx2 - bx0) * (bx3 - bx1);
            unrollN<8>([&](auto w_) {
                constexpr int W = decltype(w_)::v;
                const int c = W * 64 + lane;
                const bool pred = (c < r) &&
                    iou_pred(bx0, bx1, bx2, bx3, a1, qc0[W], qc1[W], qc2[W], qc3[W], ac[W]);
                const u64 bits = __ballot(pred);
                if (lane == 0) M[((size_t)(cls * CAP + r)) * 8 + W] = bits;
            });
        }
    }
    __threadfence();
    if (lane == 0)
        __hip_atomic_fetch_add(&ctrl[cls], 1u, __ATOMIC_RELEASE, __HIP_MEMORY_SCOPE_AGENT);

    if (((b & 3) != 0) || (wave != 0)) return;

    // ================= SCAN (wave 0 of blocks 0,4,8,12,16) =================
    if (lane == 0) { while (aload_acq(&ctrl[cls]) < 32u) {} }

    {   // stage matrix rows to LDS
        const ulonglong2* Mg = (const ulonglong2*)(M + (size_t)cls * CAP * 8);
        ulonglong2* Ml = (ulonglong2*)s_mtx;
        for (int it = lane; it < CAP * 4; it += 64) Ml[it] = Mg[it];
    }
    // preload det fields into LDS: [b0 b1 b2 b3 sc a1 g -]
    for (int rr = lane; rr < myn; rr += 64) {
        const int g = s_list[rr];
        const float* p = x + g * 6;
        const float b0 = p[0], b1 = p[1], b2 = p[2], b3 = p[3], sc = p[4];
        s_det[rr][0] = b0; s_det[rr][1] = b1; s_det[rr][2] = b2; s_det[rr][3] = b3;
        s_det[rr][4] = sc; s_det[rr][5] = (b2 - b0) * (b3 - b1);
        ((int*)s_det[rr])[6] = g;
    }

    // serial scan state: lane L owns clean clusters 8L..8L+7 (one alive byte)
    u32 aliveB = 0;
    float dm0 = 0.f, dm1 = 0.f, dm2 = 0.f, dm3 = 0.f, da = 0.f;
    float e0 = 0.f, e1 = 0.f, e2 = 0.f, e3 = 0.f, ess = 0.f;
    int drk = INF, dgi = 0, dct = 0, dirtyCnt = 0;

    auto resolve = [&](int r, u32 mC, u64 dmask, u64 balC,
                       float bx0, float bx1, float bx2, float bx3, float sc, float a1) {
        int rank_c = INF;
        if (balC) {
            const int wl = (int)__builtin_ctzll(balC);
            const u32 byte = (u32)__builtin_amdgcn_readlane((int)mC, wl);
            rank_c = wl * 8 + (int)__builtin_ctz(byte);
        }
        int rank_d = INF, wl_d = -1;
        u64 mk = dmask;
        while (mk) {
            const int l = (int)__builtin_ctzll(mk);
            mk &= mk - 1;
            const int rk = __builtin_amdgcn_readlane(drk, l);
            if (rk < rank_d) { rank_d = rk; wl_d = l; }
        }
        if (dirtyCnt > 64) {
            const int no = (dirtyCnt - 64 < 16) ? dirtyCnt - 64 : 16;
            for (int o = 0; o < no; ++o) {
                const float m0 = s_dov[o][0], m1 = s_dov[o][1];
                const float m2 = s_dov[o][2], m3 = s_dov[o][3];
                const float ar = (m2 - m0) * (m3 - m1);
                if (iou_pred(bx0, bx1, bx2, bx3, a1, m0, m1, m2, m3, ar)) {
                    const int rk = ((const int*)s_dov[o])[9];
                    if (rk < rank_d) { rank_d = rk; wl_d = 64 + o; }
                }
            }
        }
        if (rank_c == INF && rank_d == INF) {
            aliveB |= ((r >> 3) == lane) ? (1u << (r & 7)) : 0u;
        } else if (rank_c < rank_d) {
            const int rc = rank_c;
            aliveB &= ~(((rc >> 3) == lane) ? (1u << (rc & 7)) : 0u);
            const float cb0 = s_det[rc][0], cb1 = s_det[rc][1];
            const float cb2 = s_det[rc][2], cb3 = s_det[rc][3];
            const float csc = s_det[rc][4];
            const int cgi = ((const int*)s_det[rc])[6];
            // exact ref op order: solo sums fl(csc*cb), += fl(sc*bx), fl add, div
            const float ns0 = (csc * cb0) + sc * bx0;
            const float ns1 = (csc * cb1) + sc * bx1;
            const float ns2 = (csc * cb2) + sc * bx2;
            const float ns3 = (csc * cb3) + sc * bx3;
            const float nss = csc + sc;
            const float nm0 = ns0 / nss, nm1 = ns1 / nss;
            const float nm2 = ns2 / nss, nm3 = ns3 / nss;
            if (dirtyCnt < 64) {
                if (lane == dirtyCnt) {
                    dm0 = nm0; dm1 = nm1; dm2 = nm2; dm3 = nm3;
                    da = (nm2 - nm0) * (nm3 - nm1);
                    e0 = ns0; e1 = ns1; e2 = ns2; e3 = ns3; ess = nss;
                    drk = rc; dgi = cgi; dct = 2;
                }
            } else if (dirtyCnt - 64 < 16) {
                const int o = dirtyCnt - 64;
                if (lane == 0) {
                    s_dov[o][0] = nm0; s_dov[o][1] = nm1;
                    s_dov[o][2] = nm2; s_dov[o][3] = nm3;
                    s_dov[o][4] = ns0; s_dov[o][5] = ns1;
                    s_dov[o][6] = ns2; s_dov[o][7] = ns3;
                    s_dov[o][8] = nss;
                    ((int*)s_dov[o])[9] = rc; ((int*)s_dov[o])[10] = cgi;
                    ((int*)s_dov[o])[11] = 2;
                }
            }
            dirtyCnt++;
        } else {
            if (wl_d < 64) {
                if (lane == wl_d) {
                    e0 = e0 + sc * bx0; e1 = e1 + sc * bx1;
                    e2 = e2 + sc * bx2; e3 = e3 + sc * bx3;
                    ess = ess + sc; dct++;
                    dm0 = e0 / ess; dm1 = e1 / ess;
                    dm2 = e2 / ess; dm3 = e3 / ess;
                    da = (dm2 - dm0) * (dm3 - dm1);
                }
            } else {
                const int o = wl_d - 64;
                const float f0 = s_dov[o][4] + sc * bx0;
                const float f1 = s_dov[o][5] + sc * bx1;
                const float f2 = s_dov[o][6] + sc * bx2;
                const float f3 = s_dov[o][7] + sc * bx3;
                const float fs = s_dov[o][8] + sc;
                if (lane == 0) {
                    s_dov[o][0] = f0 / fs; s_dov[o][1] = f1 / fs;
                    s_dov[o][2] = f2 / fs; s_dov[o][3] = f3 / fs;
                    s_dov[o][4] = f0; s_dov[o][5] = f1;
                    s_dov[o][6] = f2; s_dov[o][7] = f3;
                    s_dov[o][8] = fs;
                    ((int*)s_dov[o])[11] += 1;
                }
            }
        }
    };

    if (myn > 0) {
        float4 dA = *(const float4*)&s_det[0][0];
        float2 eA = *(const float2*)&s_det[0][4];
        const int i1 = (myn > 1) ? 1 : 0;
        float4 dB = *(const float4*)&s_det[i1][0];
        float2 eB = *(const float2*)&s_det[i1][4];
        u32 rowA = (u32)s_mtx[0 * 64 + lane];
        u32 rowB = (u32)s_mtx[i1 * 64 + lane];

        int r = 0;
        while (r < myn) {
            const int rn2 = (r + 2 < myn) ? r + 2 : myn - 1;
            const int rn3 = (r + 3 < myn) ? r + 3 : rn2;
            const float4 pd2 = *(const float4*)&s_det[rn2][0];
            const float2 pe2 = *(const float2*)&s_det[rn2][4];
            const float4 pd3 = *(const float4*)&s_det[rn3][0];
            const float2 pe3 = *(const float2*)&s_det[rn3][4];
            const u32 prow2 = (u32)s_mtx[rn2 * 64 + lane];
            const u32 prow3 = (u32)s_mtx[rn3 * 64 + lane];

            const bool paired = (r + 1 < myn) && (dirtyCnt <= 64);
            if (paired) {
                // speculative pair: dirty preds for both dets vs pre-r dirty state
                u64 dmA = 0ull, dmB = 0ull;
                if (dirtyCnt > 0) {
                    const bool pa = (lane < dirtyCnt) &&
                        iou_pred(dA.x, dA.y, dA.z, dA.w, eA.y, dm0, dm1, dm2, dm3, da);
                    const bool pb = (lane < dirtyCnt) &&
                        iou_pred(dB.x, dB.y, dB.z, dB.w, eB.y, dm0, dm1, dm2, dm3, da);
                    dmA = __ballot(pa); dmB = __ballot(pb);
                }
                const u32 mCa = rowA & aliveB;
                const u64 balCa = __ballot(mCa != 0u);
                if ((balCa | dmA) == 0ull) {
                    // r creates (clean) -> dirty state untouched, r+1 spec stays valid
                    aliveB |= ((r >> 3) == lane) ? (1u << (r & 7)) : 0u;
                    const u32 mCb = rowB & aliveB;   // includes r's new cluster
                    const u64 balCb = __ballot(mCb != 0u);
                    if ((balCb | dmB) == 0ull) {
                        aliveB |= (((r + 1) >> 3) == lane) ? (1u << ((r + 1) & 7)) : 0u;
                    } else {
                        resolve(r + 1, mCb, dmB, balCb, dB.x, dB.y, dB.z, dB.w, eB.x, eB.y);
                    }
                } else {
                    // r matches: resolve serially, then reprocess r+1 from scratch
                    resolve(r, mCa, dmA, balCa, dA.x, dA.y, dA.z, dA.w, eA.x, eA.y);
                    u64 dmB2 = 0ull;
                    if (dirtyCnt > 0) {
                        const bool pb2 = (lane < dirtyCnt) &&
                            iou_pred(dB.x, dB.y, dB.z, dB.w, eB.y, dm0, dm1, dm2, dm3, da);
                        dmB2 = __ballot(pb2);
                    }
                    const u32 mCb2 = rowB & aliveB;
                    const u64 balCb2 = __ballot(mCb2 != 0u);
                    if ((balCb2 | dmB2) == 0ull) {
                        aliveB |= (((r + 1) >> 3) == lane) ? (1u << ((r + 1) & 7)) : 0u;
                    } else {
                        resolve(r + 1, mCb2, dmB2, balCb2, dB.x, dB.y, dB.z, dB.w, eB.x, eB.y);
                    }
                }
                r += 2;
                dA = pd2; eA = pe2; rowA = prow2;
                dB = pd3; eB = pe3; rowB = prow3;
            } else {
                u64 dmA2 = 0ull;
                if (dirtyCnt > 0) {
                    const bool pa2 = (lane < dirtyCnt) &&
                        iou_pred(dA.x, dA.y, dA.z, dA.w, eA.y, dm0, dm1, dm2, dm3, da);
                    dmA2 = __ballot(pa2);
                }
                const u32 mCa2 = rowA & aliveB;
                const u64 balCa2 = __ballot(mCa2 != 0u);
                if ((balCa2 | dmA2) == 0ull) {
                    aliveB |= ((r >> 3) == lane) ? (1u << (r & 7)) : 0u;
                } else {
                    resolve(r, mCa2, dmA2, balCa2, dA.x, dA.y, dA.z, dA.w, eA.x, eA.y);
                }
                r += 1;
                dA = dB; eA = eB; rowA = rowB;
                dB = pd2; eB = pe2; rowB = prow2;
            }
        }
    }

    // ---- emit compacted records: clean (solo mean, score=sc) then dirty ----
    int wo = 0;
    for (int Kw = 0; Kw < 8; ++Kw) {
        u64 am = 0ull;
        #pragma unroll
        for (int bb = 0; bb < 8; ++bb)
            am |= (u64)(u32)(u8)__builtin_amdgcn_readlane((int)aliveB, Kw * 8 + bb) << (8 * bb);
        const int j = Kw * 64 + lane;
        const bool pred = (am >> lane) & 1ull;
        if (pred) {
            const int pos = wo + (int)__popcll(am & (((u64)1 << lane) - 1));
            const float b0 = s_det[j][0], b1 = s_det[j][1];
            const float b2 = s_det[j][2], b3 = s_det[j][3];
            const float sc = s_det[j][4];
            const int g = ((const int*)s_det[j])[6];
            float* rec = recs + (size_t)(cls * CAP + pos) * 8;
            rec[0] = (sc * b0) / sc; rec[1] = (sc * b1) / sc;
            rec[2] = (sc * b2) / sc; rec[3] = (sc * b3) / sc;
            rec[4] = sc;
            ((int*)rec)[5] = g;
        }
        wo += (int)__popcll(am);
    }
    const int nreg = (dirtyCnt < 64) ? dirtyCnt : 64;
    if (lane < nreg) {
        float* rec = recs + (size_t)(cls * CAP + wo + lane) * 8;
        rec[0] = dm0; rec[1] = dm1; rec[2] = dm2; rec[3] = dm3;
        rec[4] = ess / (float)dct;          // exact IEEE div
        ((int*)rec)[5] = dgi;
    }
    const int nov = (dirtyCnt > 64) ? ((dirtyCnt - 64 < 16) ? dirtyCnt - 64 : 16) : 0;
    for (int o = 0; o < nov; ++o) {
        if (lane == 0) {
            float* rec = recs + (size_t)(cls * CAP + wo + nreg + o) * 8;
            rec[0] = s_dov[o][0]; rec[1] = s_dov[o][1];
            rec[2] = s_dov[o][2]; rec[3] = s_dov[o][3];
            rec[4] = s_dov[o][8] / (float)(((const int*)s_dov[o])[11]);
            ((int*)rec)[5] = ((const int*)s_dov[o])[10];
        }
    }
    if (lane == 0) cnts[cls] = wo + nreg + nov;
    __threadfence();
    if (lane == 0)
        __hip_atomic_fetch_add(&ctrl[16], 1u, __ATOMIC_RELEASE, __HIP_MEMORY_SCOPE_AGENT);
}

extern "C" void kernel_launch(void* const* d_in, const int* in_sizes, int n_in,
                              void* d_out, int out_size, void* d_ws, size_t ws_size,
                              hipStream_t stream) {
    const float* x = (const float*)d_in[0];
    float* out = (float*)d_out;
    // ws layout: M 160 KB | ctrl 256 B | cnts 256 B | recs 80 KB
    u64* M      = (u64*)d_ws;
    u32* ctrl   = (u32*)((char*)d_ws + (size_t)NCLS * CAP * 8 * 8);
    int* cnts   = (int*)((char*)d_ws + (size_t)NCLS * CAP * 8 * 8 + 256);
    float* recs = (float*)((char*)d_ws + (size_t)NCLS * CAP * 8 * 8 + 512);
    wbf_all<<<NBLK, 512, 0, stream>>>(x, M, ctrl, recs, cnts, out);
}

// Round 14
// 126.639 us; speedup vs baseline: 2.6272x; 1.5559x over previous
//
#include <hip/hip_runtime.h>

typedef unsigned long long u64;
typedef unsigned short u16;
typedef unsigned u32;
typedef unsigned char u8;

#define PRE   2000
#define POST  300
#define NCLS  5
#define CAP   512
#define INF   0x7fffffff
#define MAGIC 0x13579BDFu
#define NBLK  21
#define SORTB 20

// Exact threshold midpoint: fl32(inter/uni) > 0.55f  <=>  inter >= MID*uni (uni>0).
// MID = 0.55f + 2^-25; MID*(24-bit uni) exact in f64 -> bit-exact predicate.
// Validated: absmax == 0.0 in rounds 3-13.
#define MID 0x1.19999A8p-1

template <int K> struct IC { static constexpr int v = K; };
template <int N, typename F> __device__ __forceinline__ void unrollN(F&& f) {
    if constexpr (N > 0) { unrollN<N - 1>(f); f(IC<N - 1>{}); }
}

__device__ __forceinline__ u32 aload_acq(u32* p) {
    return __hip_atomic_load(p, __ATOMIC_ACQUIRE, __HIP_MEMORY_SCOPE_AGENT);
}

__device__ __forceinline__ bool iou_pred(float bx0, float bx1, float bx2, float bx3,
                                         float a1, float m0, float m1, float m2, float m3,
                                         float a2) {
    const float ltx = fmaxf(bx0, m0), lty = fmaxf(bx1, m1);
    const float rbx = fminf(bx2, m2), rby = fminf(bx3, m3);
    const float wd = fmaxf(rbx - ltx, 0.f), hg = fmaxf(rby - lty, 0.f);
    const float inter = wd * hg;
    const float uni = (a1 + a2) - inter;
    return (uni > 0.f) && ((double)inter >= MID * (double)uni);
}

// Blocks 0-19: matrix (cls=b>>2, 8 slices/block); wave0 of b%4==0 scans its class
// after a spin barrier; block 20 sorts after all 5 scans complete.
__global__ __launch_bounds__(512, 1) void wbf_all(const float* __restrict__ x,
                                                  u64* __restrict__ M,
                                                  u32* __restrict__ ctrl,
                                                  float* __restrict__ recs,
                                                  int* __restrict__ cnts,
                                                  float* __restrict__ out) {
#pragma clang fp contract(off)
    __shared__ __align__(16) char s_buf[58400];
    u8*  s_mtx = (u8*)s_buf;                                 // 32768
    float (*s_det)[8]  = (float (*)[8])(s_buf + 32768);      // 16384
    float (*s_dov)[16] = (float (*)[16])(s_buf + 49152);     // 8192: dirty clusters
    u16* s_list        = (u16*)(s_buf + 57344);              // 1024
    int* s_myn         = (int*)(s_buf + 58368);

    const int tid  = threadIdx.x;
    const int lane = tid & 63;
    const int wave = tid >> 6;
    const int b    = blockIdx.x;

    // ---- init handshake (ws re-poisoned 0xAA before every launch) ----
    if (b == 0) {
        if (tid == 0) {
            for (int i = 0; i < NCLS; ++i)
                __hip_atomic_store(&ctrl[i], 0u, __ATOMIC_RELAXED, __HIP_MEMORY_SCOPE_AGENT);
            __hip_atomic_store(&ctrl[16], 0u, __ATOMIC_RELAXED, __HIP_MEMORY_SCOPE_AGENT);
            __hip_atomic_store(&ctrl[32], MAGIC, __ATOMIC_RELEASE, __HIP_MEMORY_SCOPE_AGENT);
        }
    } else {
        if (tid == 0) { while (aload_acq(&ctrl[32]) != MAGIC) {} }
    }
    __syncthreads();

    // ================= SORT BLOCK (R13 proven) =================
    if (b == SORTB) {
        u64* keys = (u64*)s_buf;             // 16384
        u32* hist = (u32*)(s_buf + 16384);   // 16384
        u64* cand = (u64*)(s_buf + 32768);   // 4096
        u32* part = (u32*)(s_buf + 36864);   // 2048
        int* scal = (int*)(s_buf + 38912);

        if (tid == 0) { while (aload_acq(&ctrl[16]) < (u32)NCLS) {} }
        __syncthreads();

        int c[NCLS], off[NCLS];
        int n = 0;
        #pragma unroll
        for (int w = 0; w < NCLS; ++w) { c[w] = cnts[w]; off[w] = n; n += c[w]; }
        if (n > 2048) n = 2048;

        #pragma unroll
        for (int w = 0; w < NCLS; ++w) {
            const int cw = c[w], ow = off[w];
            for (int j = tid; j < cw; j += 512) {
                const float* r = recs + (size_t)(w * CAP + j) * 8;
                const unsigned sb = __float_as_uint(r[4]);
                const int g = ((const int*)r)[5];
                const int id = w * CAP + j;
                u64 key = ((u64)sb << 32) | ((u64)(unsigned)(0xFFFF - g) << 16) | (u64)id;
                keys[ow + j] = ~key;
            }
        }
        for (int i = n + tid; i < 2048; i += 512) keys[i] = ~0ull;
        for (int h = tid; h < 4096; h += 512) hist[h] = 0u;
        __syncthreads();

        for (int i = tid; i < n; i += 512)
            atomicAdd(&hist[(u32)(keys[i] >> 52)], 1u);
        __syncthreads();

        const int target = (POST < n) ? POST : n;
        u32 p = 0;
        #pragma unroll
        for (int k = 0; k < 8; ++k) p += hist[tid * 8 + k];
        part[tid] = p;
        __syncthreads();
        for (int o2 = 1; o2 < 512; o2 <<= 1) {
            const u32 v = part[tid];
            const u32 add = (tid >= o2) ? part[tid - o2] : 0u;
            __syncthreads();
            part[tid] = v + add;
            __syncthreads();
        }
        const u32 I = part[tid];
        const u32 E = I - p;
        if ((int)E < target && (int)I >= target) { scal[0] = tid; scal[1] = (int)E; }
        if (tid == 0) scal[2] = 0;
        __syncthreads();
        const int T = scal[0];
        int cum = scal[1];
        int B = T * 8 + 7;
        for (int bb = T * 8; bb < T * 8 + 8; ++bb) {
            const int h = (int)hist[bb];
            if (cum + h >= target) { B = bb; break; }
            cum += h;
        }
        const int candCount = cum + (int)hist[B];

        if (candCount <= 512) {
            for (int i = tid; i < n; i += 512) {
                const u64 kk = keys[i];
                if ((int)(u32)(kk >> 52) <= B) {
                    const int pos = atomicAdd(&scal[2], 1);
                    cand[pos] = kk;
                }
            }
            __syncthreads();
            if (tid >= candCount) cand[tid] = ~0ull;
            __syncthreads();
            for (int kk2 = 2; kk2 <= 512; kk2 <<= 1) {
                for (int jj = kk2 >> 1; jj > 0; jj >>= 1) {
                    const int i = tid, ixj = i ^ jj;
                    if (ixj > i) {
                        const u64 a = cand[i], bb2 = cand[ixj];
                        const bool up = ((i & kk2) == 0);
                        if ((a > bb2) == up) { cand[i] = bb2; cand[ixj] = a; }
                    }
                    __syncthreads();
                }
            }
            if (tid < POST) {
                float* o = out + tid * 6;
                if (tid < target) {
                    const u64 key = ~cand[tid];
                    const int id = (int)(key & 0xFFFFull);
                    const float* rec = recs + (size_t)id * 8;
                    o[0] = rec[0]; o[1] = rec[1]; o[2] = rec[2]; o[3] = rec[3];
                    o[4] = __uint_as_float((unsigned)(key >> 32));
                    o[5] = (float)(id >> 9);
                } else {
                    o[0] = 0.f; o[1] = 0.f; o[2] = 0.f; o[3] = 0.f; o[4] = 0.f; o[5] = 0.f;
                }
            }
        } else {
            for (int kk2 = 2; kk2 <= 2048; kk2 <<= 1) {
                for (int jj = kk2 >> 1; jj > 0; jj >>= 1) {
                    for (int i = tid; i < 2048; i += 512) {
                        const int ixj = i ^ jj;
                        if (ixj > i) {
                            const u64 a = keys[i], bb2 = keys[ixj];
                            const bool up = ((i & kk2) == 0);
                            if ((a > bb2) == up) { keys[i] = bb2; keys[ixj] = a; }
                        }
                    }
                    __syncthreads();
                }
            }
            if (tid < POST) {
                float* o = out + tid * 6;
                if (tid < target) {
                    const u64 key = ~keys[tid];
                    const int id = (int)(key & 0xFFFFull);
                    const float* rec = recs + (size_t)id * 8;
                    o[0] = rec[0]; o[1] = rec[1]; o[2] = rec[2]; o[3] = rec[3];
                    o[4] = __uint_as_float((unsigned)(key >> 32));
                    o[5] = (float)(id >> 9);
                } else {
                    o[0] = 0.f; o[1] = 0.f; o[2] = 0.f; o[3] = 0.f; o[4] = 0.f; o[5] = 0.f;
                }
            }
        }
        return;
    }

    // ================= MATRIX BLOCKS (0..19, R13 proven) =================
    const int cls = b >> 2;
    const float mycls = (float)cls;

    if (wave == 0) {
        int mn = 0;
        for (int t0 = 0; t0 < PRE; t0 += 64) {
            const int t = t0 + lane;
            const bool pp = (t < PRE) && (x[t * 6 + 5] == mycls);
            const u64 mask = __ballot(pp);
            const int pos = mn + __popcll(mask & (((u64)1 << lane) - 1));
            if (pp && pos < CAP) s_list[pos] = (u16)t;
            mn += __popcll(mask);
        }
        if (mn > CAP) mn = CAP;
        if (lane == 0) *s_myn = mn;
    }
    __syncthreads();
    const int myn = *s_myn;

    {
        float qc0[8], qc1[8], qc2[8], qc3[8], ac[8];
        unrollN<8>([&](auto k_) {
            constexpr int K = decltype(k_)::v;
            const int c = K * 64 + lane;
            qc0[K] = 0.f; qc1[K] = 0.f; qc2[K] = 0.f; qc3[K] = 0.f; ac[K] = 0.f;
            if (c < myn) {
                const int g = s_list[c];
                const float* p = x + g * 6;
                const float b0 = p[0], b1 = p[1], b2 = p[2], b3 = p[3], sc = p[4];
                qc0[K] = (sc * b0) / sc; qc1[K] = (sc * b1) / sc;
                qc2[K] = (sc * b2) / sc; qc3[K] = (sc * b3) / sc;
                ac[K] = (qc2[K] - qc0[K]) * (qc3[K] - qc1[K]);
            }
        });
        const int slice = (b & 3) * 8 + wave;
        const int rlo = slice * 16;
        const int rhi = (rlo + 16 < myn) ? rlo + 16 : myn;
        for (int r = rlo; r < rhi; ++r) {
            const int g = s_list[r];
            const float* p = x + g * 6;
            const float bx0 = p[0], bx1 = p[1], bx2 = p[2], bx3 = p[3];
            const float a1 = (bx2 - bx0) * (bx3 - bx1);
            unrollN<8>([&](auto w_) {
                constexpr int W = decltype(w_)::v;
                const int c = W * 64 + lane;
                const bool pred = (c < r) &&
                    iou_pred(bx0, bx1, bx2, bx3, a1, qc0[W], qc1[W], qc2[W], qc3[W], ac[W]);
                const u64 bits = __ballot(pred);
                if (lane == 0) M[((size_t)(cls * CAP + r)) * 8 + W] = bits;
            });
        }
    }
    __threadfence();
    if (lane == 0)
        __hip_atomic_fetch_add(&ctrl[cls], 1u, __ATOMIC_RELEASE, __HIP_MEMORY_SCOPE_AGENT);

    if (((b & 3) != 0) || (wave != 0)) return;

    // ================= SCAN (wave 0 of blocks 0,4,8,12,16) =================
    if (lane == 0) { while (aload_acq(&ctrl[cls]) < 32u) {} }

    {   // stage matrix rows to LDS
        const ulonglong2* Mg = (const ulonglong2*)(M + (size_t)cls * CAP * 8);
        ulonglong2* Ml = (ulonglong2*)s_mtx;
        for (int it = lane; it < CAP * 4; it += 64) Ml[it] = Mg[it];
    }
    // preload det fields into LDS: [b0 b1 b2 b3 sc a1 g -]
    for (int rr = lane; rr < myn; rr += 64) {
        const int g = s_list[rr];
        const float* p = x + g * 6;
        const float b0 = p[0], b1 = p[1], b2 = p[2], b3 = p[3], sc = p[4];
        s_det[rr][0] = b0; s_det[rr][1] = b1; s_det[rr][2] = b2; s_det[rr][3] = b3;
        s_det[rr][4] = sc; s_det[rr][5] = (b2 - b0) * (b3 - b1);
        ((int*)s_det[rr])[6] = g;
    }

    // scan state: lane L owns clean clusters 8L..8L+7; dirty clusters in s_dov rows
    // s_dov row: [0..3] mean, [4] area, [5..8] sums, [9] ss, [10] rc, [11] g, [12] cnt
    u32 aliveB = 0;
    int dirtyCnt = 0;
    bool consA = false;
    int resCode = 0, resIdx = 0;

    auto resolve = [&](int r) {
        const float bx0 = s_det[r][0], bx1 = s_det[r][1];
        const float bx2 = s_det[r][2], bx3 = s_det[r][3];
        const float sc = s_det[r][4], a1 = s_det[r][5];
        const u32 rowByte = (u32)s_mtx[(size_t)r * 64 + lane];
        const u32 mC = rowByte & aliveB;
        const u64 balC = __ballot(mC != 0u);
        int rank_c = INF;
        if (balC) {
            const int wl = (int)__builtin_ctzll(balC);
            const u32 byte = (u32)__builtin_amdgcn_readlane((int)mC, wl);
            rank_c = wl * 8 + (int)__builtin_ctz(byte);
        }
        int rank_d = INF, di = -1;
        if (dirtyCnt > 0) {
            bool p = false; int myrk = INF;
            if (lane < dirtyCnt) {
                const float* dv = s_dov[lane];
                p = iou_pred(bx0, bx1, bx2, bx3, a1, dv[0], dv[1], dv[2], dv[3], dv[4]);
                myrk = ((const int*)dv)[10];
            }
            u64 mk = __ballot(p);
            while (mk) {
                const int l = (int)__builtin_ctzll(mk);
                mk &= mk - 1;
                const int rk = __builtin_amdgcn_readlane(myrk, l);
                if (rk < rank_d) { rank_d = rk; di = l; }
            }
            for (int dd = 64; dd < dirtyCnt; ++dd) {   // rare (>64 dirty)
                const float* dv = s_dov[dd];
                if (iou_pred(bx0, bx1, bx2, bx3, a1, dv[0], dv[1], dv[2], dv[3], dv[4])) {
                    const int rk = ((const int*)dv)[10];
                    if (rk < rank_d) { rank_d = rk; di = dd; }
                }
            }
        }
        if (rank_c == INF && rank_d == INF) {
            aliveB |= ((r >> 3) == lane) ? (1u << (r & 7)) : 0u;
            resCode = 0;
        } else if (rank_c < rank_d) {
            const int rc = rank_c;
            aliveB &= ~(((rc >> 3) == lane) ? (1u << (rc & 7)) : 0u);
            const float cb0 = s_det[rc][0], cb1 = s_det[rc][1];
            const float cb2 = s_det[rc][2], cb3 = s_det[rc][3];
            const float csc = s_det[rc][4];
            const int cgi = ((const int*)s_det[rc])[6];
            // exact ref op order: solo sums fl(csc*cb), += fl(sc*bx), add, div
            const float ns0 = (csc * cb0) + sc * bx0;
            const float ns1 = (csc * cb1) + sc * bx1;
            const float ns2 = (csc * cb2) + sc * bx2;
            const float ns3 = (csc * cb3) + sc * bx3;
            const float nss = csc + sc;
            const float nm0 = ns0 / nss, nm1 = ns1 / nss;
            const float nm2 = ns2 / nss, nm3 = ns3 / nss;
            const int D = dirtyCnt;
            if (lane == 0 && D < 128) {
                float* dv = s_dov[D];
                dv[0] = nm0; dv[1] = nm1; dv[2] = nm2; dv[3] = nm3;
                dv[4] = (nm2 - nm0) * (nm3 - nm1);
                dv[5] = ns0; dv[6] = ns1; dv[7] = ns2; dv[8] = ns3; dv[9] = nss;
                ((int*)dv)[10] = rc; ((int*)dv)[11] = cgi; ((int*)dv)[12] = 2;
            }
            dirtyCnt++;
            resCode = 1; resIdx = D;
        } else {
            const float* dv = s_dov[di];
            const float f0 = dv[5] + sc * bx0, f1 = dv[6] + sc * bx1;
            const float f2 = dv[7] + sc * bx2, f3 = dv[8] + sc * bx3;
            const float fs = dv[9] + sc;
            const float nm0 = f0 / fs, nm1 = f1 / fs, nm2 = f2 / fs, nm3 = f3 / fs;
            const int nct = ((const int*)dv)[12] + 1;
            if (lane == 0) {
                float* dw = s_dov[di];
                dw[0] = nm0; dw[1] = nm1; dw[2] = nm2; dw[3] = nm3;
                dw[4] = (nm2 - nm0) * (nm3 - nm1);
                dw[5] = f0; dw[6] = f1; dw[7] = f2; dw[8] = f3; dw[9] = fs;
                ((int*)dw)[12] = nct;
            }
            resCode = 2; resIdx = di;
        }
    };

    // ---- batched scan: 64-det chunks, skip runs of guaranteed-creates ----
    unrollN<8>([&](auto k_) {
        constexpr int K = decltype(k_)::v;
        const int r0 = K * 64;
        if (r0 < myn) {
            const int cnt = (myn - r0 < 64) ? (myn - r0) : 64;
            const bool valid = lane < cnt;
            // rowNE bit: my row (r0+lane) has any matrix bit set (conservative clean test)
            u64 orv = 0ull;
            {
                const int rr = r0 + (valid ? lane : 0);
                const u64* rp = (const u64*)&s_mtx[(size_t)rr * 64];
                orv = rp[0] | rp[1] | rp[2] | rp[3] | rp[4] | rp[5] | rp[6] | rp[7];
            }
            const u64 rowW = __ballot(valid && orv != 0ull);
            // my det fields
            float4 db = make_float4(0.f, 0.f, 0.f, 0.f);
            float2 de = make_float2(1.f, 0.f);
            if (valid) {
                db = *(const float4*)&s_det[r0 + lane][0];
                de = *(const float2*)&s_det[r0 + lane][4];
            }
            // dirty-match mask: bit d = my det matches dirty cluster d (exact)
            u64 dmask = 0ull;
            if (!consA) {
                const int DN = (dirtyCnt < 64) ? dirtyCnt : 64;
                for (int d = 0; d < DN; ++d) {
                    const float* dv = s_dov[d];
                    const bool pp = valid && iou_pred(db.x, db.y, db.z, db.w, de.y,
                                                     dv[0], dv[1], dv[2], dv[3], dv[4]);
                    if (pp) dmask |= 1ull << d;
                }
            }
            int p = 0;
            while (p < cnt) {
                const bool myviol = valid && (lane >= p) &&
                    (consA || dmask != 0ull || ((rowW >> lane) & 1ull));
                const u64 vb = __ballot(myviol);
                const int F = vb ? (int)__builtin_ctzll(vb) : cnt;
                {   // commit creates [r0+p, r0+F): one masked OR per lane
                    const int lo = r0 + p, h2 = r0 + F;
                    int s = lo - 8 * lane; s = (s > 0) ? s : 0;
                    int e = h2 - 8 * lane; e = (e < 8) ? e : 8;
                    if (e > s) aliveB |= ((0xFFu >> (8 - (e - s))) << s);
                }
                if (F >= cnt) break;
                const int r = r0 + F;
                // quick exact check: clean row&alive, dirty via maintained dmask
                const u32 rowByte = (u32)s_mtx[(size_t)r * 64 + lane];
                const u64 balC = __ballot((rowByte & aliveB) != 0u);
                const u64 danyb = __ballot(dmask != 0ull);
                const bool Fdirty = consA || (((danyb >> F) & 1ull) != 0ull);
                if (!Fdirty && balC == 0ull) {
                    aliveB |= ((r >> 3) == lane) ? (1u << (r & 7)) : 0u;   // create
                } else {
                    resolve(r);
                    if (resCode != 0) {
                        const int idx = resIdx;
                        if (idx < 64) {
                            const float* dv = s_dov[idx];
                            const bool pnew = valid && (lane > F) &&
                                iou_pred(db.x, db.y, db.z, db.w, de.y,
                                         dv[0], dv[1], dv[2], dv[3], dv[4]);
                            const u64 nb = __ballot(pnew);
                            dmask = (dmask & ~(1ull << idx)) | (((nb >> lane) & 1ull) << idx);
                        } else {
                            consA = true;   // beyond mask capacity: exact-serial rest
                        }
                    }
                }
                p = F + 1;
            }
        }
    });

    // ---- emit compacted records: clean (solo mean, score=sc) then dirty ----
    int wo = 0;
    for (int Kw = 0; Kw < 8; ++Kw) {
        u64 am = 0ull;
        #pragma unroll
        for (int bb = 0; bb < 8; ++bb)
            am |= (u64)(u32)(u8)__builtin_amdgcn_readlane((int)aliveB, Kw * 8 + bb) << (8 * bb);
        const int j = Kw * 64 + lane;
        const bool pred = (am >> lane) & 1ull;
        if (pred) {
            const int pos = wo + (int)__popcll(am & (((u64)1 << lane) - 1));
            const float b0 = s_det[j][0], b1 = s_det[j][1];
            const float b2 = s_det[j][2], b3 = s_det[j][3];
            const float sc = s_det[j][4];
            const int g = ((const int*)s_det[j])[6];
            float* rec = recs + (size_t)(cls * CAP + pos) * 8;
            rec[0] = (sc * b0) / sc; rec[1] = (sc * b1) / sc;
            rec[2] = (sc * b2) / sc; rec[3] = (sc * b3) / sc;
            rec[4] = sc;
            ((int*)rec)[5] = g;
        }
        wo += (int)__popcll(am);
    }
    const int demit = (dirtyCnt < 128) ? dirtyCnt : 128;
    for (int d = lane; d < demit; d += 64) {
        const float* dv = s_dov[d];
        float* rec = recs + (size_t)(cls * CAP + wo + d) * 8;
        rec[0] = dv[0]; rec[1] = dv[1]; rec[2] = dv[2]; rec[3] = dv[3];
        rec[4] = dv[9] / (float)(((const int*)dv)[12]);   // exact IEEE div
        ((int*)rec)[5] = ((const int*)dv)[11];
    }
    if (lane == 0) cnts[cls] = wo + demit;
    __threadfence();
    if (lane == 0)
        __hip_atomic_fetch_add(&ctrl[16], 1u, __ATOMIC_RELEASE, __HIP_MEMORY_SCOPE_AGENT);
}

extern "C" void kernel_launch(void* const* d_in, const int* in_sizes, int n_in,
                              void* d_out, int out_size, void* d_ws, size_t ws_size,
                              hipStream_t stream) {
    const float* x = (const float*)d_in[0];
    float* out = (float*)d_out;
    // ws layout: M 160 KB | ctrl 256 B | cnts 256 B | recs 80 KB
    u64* M      = (u64*)d_ws;
    u32* ctrl   = (u32*)((char*)d_ws + (size_t)NCLS * CAP * 8 * 8);
    int* cnts   = (int*)((char*)d_ws + (size_t)NCLS * CAP * 8 * 8 + 256);
    float* recs = (float*)((char*)d_ws + (size_t)NCLS * CAP * 8 * 8 + 512);
    wbf_all<<<NBLK, 512, 0, stream>>>(x, M, ctrl, recs, cnts, out);
}

// Round 15
// 126.357 us; speedup vs baseline: 2.6331x; 1.0022x over previous
//
#include <hip/hip_runtime.h>

typedef unsigned long long u64;
typedef unsigned short u16;
typedef unsigned u32;
typedef unsigned char u8;

#define PRE   2000
#define POST  300
#define NCLS  5
#define CAP   512
#define INF   0x7fffffff
#define MAGIC 0x13579BDFu
#define NBLK  21
#define SORTB 20

// Exact threshold midpoint: fl32(inter/uni) > 0.55f  <=>  inter >= MID*uni (uni>0).
// MID = 0.55f + 2^-25; MID*(24-bit uni) exact in f64 -> bit-exact predicate.
// Validated: absmax == 0.0 in rounds 3-14.
#define MID 0x1.19999A8p-1

template <int K> struct IC { static constexpr int v = K; };
template <int N, typename F> __device__ __forceinline__ void unrollN(F&& f) {
    if constexpr (N > 0) { unrollN<N - 1>(f); f(IC<N - 1>{}); }
}

__device__ __forceinline__ u32 aload_acq(u32* p) {
    return __hip_atomic_load(p, __ATOMIC_ACQUIRE, __HIP_MEMORY_SCOPE_AGENT);
}

__device__ __forceinline__ bool iou_pred(float bx0, float bx1, float bx2, float bx3,
                                         float a1, float m0, float m1, float m2, float m3,
                                         float a2) {
    const float ltx = fmaxf(bx0, m0), lty = fmaxf(bx1, m1);
    const float rbx = fminf(bx2, m2), rby = fminf(bx3, m3);
    const float wd = fmaxf(rbx - ltx, 0.f), hg = fmaxf(rby - lty, 0.f);
    const float inter = wd * hg;
    const float uni = (a1 + a2) - inter;
    return (uni > 0.f) && ((double)inter >= MID * (double)uni);
}

// Blocks 0-19: matrix (cls=b>>2, 8 slices/block); wave0 of b%4==0 scans its class
// after a spin barrier; block 20 sorts after all 5 scans complete.
__global__ __launch_bounds__(512, 1) void wbf_all(const float* __restrict__ x,
                                                  u64* __restrict__ M,
                                                  u32* __restrict__ ctrl,
                                                  float* __restrict__ recs,
                                                  int* __restrict__ cnts,
                                                  float* __restrict__ out) {
#pragma clang fp contract(off)
    __shared__ __align__(16) char s_buf[58448];
    u8*  s_mtx = (u8*)s_buf;                                 // 32768
    float (*s_det)[8]  = (float (*)[8])(s_buf + 32768);      // 16384
    float (*s_dov)[16] = (float (*)[16])(s_buf + 49152);     // 8192: dirty clusters
    u16* s_list        = (u16*)(s_buf + 57344);              // 1024
    int* s_myn         = (int*)(s_buf + 58368);
    u8*  s_ab          = (u8*)(s_buf + 58376);               // 64: shared alive bytes

    const int tid  = threadIdx.x;
    const int lane = tid & 63;
    const int wave = tid >> 6;
    const int b    = blockIdx.x;

    // ---- init handshake (ws re-poisoned 0xAA before every launch) ----
    if (b == 0) {
        if (tid == 0) {
            for (int i = 0; i < NCLS; ++i)
                __hip_atomic_store(&ctrl[i], 0u, __ATOMIC_RELAXED, __HIP_MEMORY_SCOPE_AGENT);
            __hip_atomic_store(&ctrl[16], 0u, __ATOMIC_RELAXED, __HIP_MEMORY_SCOPE_AGENT);
            __hip_atomic_store(&ctrl[32], MAGIC, __ATOMIC_RELEASE, __HIP_MEMORY_SCOPE_AGENT);
        }
    } else {
        if (tid == 0) { while (aload_acq(&ctrl[32]) != MAGIC) {} }
    }
    __syncthreads();

    // ================= SORT BLOCK =================
    if (b == SORTB) {
        u64* keys = (u64*)s_buf;             // 16384
        u32* hist = (u32*)(s_buf + 16384);   // 16384
        u64* cand = (u64*)(s_buf + 32768);   // 4096
        u32* part = (u32*)(s_buf + 36864);   // 2048
        int* scal = (int*)(s_buf + 38912);

        // pre-init while the scans run
        for (int i = tid; i < 2048; i += 512) keys[i] = ~0ull;
        for (int h = tid; h < 4096; h += 512) hist[h] = 0u;
        if (tid == 0) scal[2] = 0;
        __syncthreads();
        if (tid == 0) { while (aload_acq(&ctrl[16]) < (u32)NCLS) {} }
        __syncthreads();

        int c[NCLS], off[NCLS];
        int n = 0;
        #pragma unroll
        for (int w = 0; w < NCLS; ++w) { c[w] = cnts[w]; off[w] = n; n += c[w]; }
        if (n > 2048) n = 2048;

        #pragma unroll
        for (int w = 0; w < NCLS; ++w) {
            const int cw = c[w], ow = off[w];
            for (int j = tid; j < cw; j += 512) {
                const float* r = recs + (size_t)(w * CAP + j) * 8;
                const unsigned sb = __float_as_uint(r[4]);
                const int g = ((const int*)r)[5];
                const int id = w * CAP + j;
                u64 key = ((u64)sb << 32) | ((u64)(unsigned)(0xFFFF - g) << 16) | (u64)id;
                keys[ow + j] = ~key;
            }
        }
        __syncthreads();

        for (int i = tid; i < n; i += 512)
            atomicAdd(&hist[(u32)(keys[i] >> 52)], 1u);
        __syncthreads();

        const int target = (POST < n) ? POST : n;
        u32 p = 0;
        #pragma unroll
        for (int k = 0; k < 8; ++k) p += hist[tid * 8 + k];
        part[tid] = p;
        __syncthreads();
        for (int o2 = 1; o2 < 512; o2 <<= 1) {
            const u32 v = part[tid];
            const u32 add = (tid >= o2) ? part[tid - o2] : 0u;
            __syncthreads();
            part[tid] = v + add;
            __syncthreads();
        }
        const u32 I = part[tid];
        const u32 E = I - p;
        if ((int)E < target && (int)I >= target) { scal[0] = tid; scal[1] = (int)E; }
        __syncthreads();
        const int T = scal[0];
        int cum = scal[1];
        int B = T * 8 + 7;
        for (int bb = T * 8; bb < T * 8 + 8; ++bb) {
            const int h = (int)hist[bb];
            if (cum + h >= target) { B = bb; break; }
            cum += h;
        }
        const int candCount = cum + (int)hist[B];

        if (candCount <= 512) {
            for (int i = tid; i < n; i += 512) {
                const u64 kk = keys[i];
                if ((int)(u32)(kk >> 52) <= B) {
                    const int pos = atomicAdd(&scal[2], 1);
                    cand[pos] = kk;
                }
            }
            __syncthreads();
            if (tid >= candCount) cand[tid] = ~0ull;
            __syncthreads();
            for (int kk2 = 2; kk2 <= 512; kk2 <<= 1) {
                for (int jj = kk2 >> 1; jj > 0; jj >>= 1) {
                    const int i = tid, ixj = i ^ jj;
                    if (ixj > i) {
                        const u64 a = cand[i], bb2 = cand[ixj];
                        const bool up = ((i & kk2) == 0);
                        if ((a > bb2) == up) { cand[i] = bb2; cand[ixj] = a; }
                    }
                    __syncthreads();
                }
            }
            if (tid < POST) {
                float* o = out + tid * 6;
                if (tid < target) {
                    const u64 key = ~cand[tid];
                    const int id = (int)(key & 0xFFFFull);
                    const float* rec = recs + (size_t)id * 8;
                    o[0] = rec[0]; o[1] = rec[1]; o[2] = rec[2]; o[3] = rec[3];
                    o[4] = __uint_as_float((unsigned)(key >> 32));
                    o[5] = (float)(id >> 9);
                } else {
                    o[0] = 0.f; o[1] = 0.f; o[2] = 0.f; o[3] = 0.f; o[4] = 0.f; o[5] = 0.f;
                }
            }
        } else {
            for (int kk2 = 2; kk2 <= 2048; kk2 <<= 1) {
                for (int jj = kk2 >> 1; jj > 0; jj >>= 1) {
                    for (int i = tid; i < 2048; i += 512) {
                        const int ixj = i ^ jj;
                        if (ixj > i) {
                            const u64 a = keys[i], bb2 = keys[ixj];
                            const bool up = ((i & kk2) == 0);
                            if ((a > bb2) == up) { keys[i] = bb2; keys[ixj] = a; }
                        }
                    }
                    __syncthreads();
                }
            }
            if (tid < POST) {
                float* o = out + tid * 6;
                if (tid < target) {
                    const u64 key = ~keys[tid];
                    const int id = (int)(key & 0xFFFFull);
                    const float* rec = recs + (size_t)id * 8;
                    o[0] = rec[0]; o[1] = rec[1]; o[2] = rec[2]; o[3] = rec[3];
                    o[4] = __uint_as_float((unsigned)(key >> 32));
                    o[5] = (float)(id >> 9);
                } else {
                    o[0] = 0.f; o[1] = 0.f; o[2] = 0.f; o[3] = 0.f; o[4] = 0.f; o[5] = 0.f;
                }
            }
        }
        return;
    }

    // ================= MATRIX BLOCKS (0..19) =================
    const int cls = b >> 2;
    const float mycls = (float)cls;

    if (wave == 0) {
        int mn = 0;
        for (int t0 = 0; t0 < PRE; t0 += 64) {
            const int t = t0 + lane;
            const bool pp = (t < PRE) && (x[t * 6 + 5] == mycls);
            const u64 mask = __ballot(pp);
            const int pos = mn + __popcll(mask & (((u64)1 << lane) - 1));
            if (pp && pos < CAP) s_list[pos] = (u16)t;
            mn += __popcll(mask);
        }
        if (mn > CAP) mn = CAP;
        if (lane == 0) *s_myn = mn;
    }
    __syncthreads();
    const int myn = *s_myn;

    {
        float qc0[8], qc1[8], qc2[8], qc3[8], ac[8];
        unrollN<8>([&](auto k_) {
            constexpr int K = decltype(k_)::v;
            const int c = K * 64 + lane;
            qc0[K] = 0.f; qc1[K] = 0.f; qc2[K] = 0.f; qc3[K] = 0.f; ac[K] = 0.f;
            if (c < myn) {
                const int g = s_list[c];
                const float* p = x + g * 6;
                const float b0 = p[0], b1 = p[1], b2 = p[2], b3 = p[3], sc = p[4];
                qc0[K] = (sc * b0) / sc; qc1[K] = (sc * b1) / sc;
                qc2[K] = (sc * b2) / sc; qc3[K] = (sc * b3) / sc;
                ac[K] = (qc2[K] - qc0[K]) * (qc3[K] - qc1[K]);
            }
        });
        const int slice = (b & 3) * 8 + wave;
        const int rlo = slice * 16;
        const int rhi = (rlo + 16 < myn) ? rlo + 16 : myn;
        for (int r = rlo; r < rhi; ++r) {
            const int g = s_list[r];
            const float* p = x + g * 6;
            const float bx0 = p[0], bx1 = p[1], bx2 = p[2], bx3 = p[3];
            const float a1 = (bx2 - bx0) * (bx3 - bx1);
            const int Wmax = r >> 6;   // words > Wmax have no bits c<r: skip entirely
            unrollN<8>([&](auto w_) {
                constexpr int W = decltype(w_)::v;
                if (W <= Wmax) {
                    const int c = W * 64 + lane;
                    const bool pred = (c < r) &&
                        iou_pred(bx0, bx1, bx2, bx3, a1, qc0[W], qc1[W], qc2[W], qc3[W], ac[W]);
                    const u64 bits = __ballot(pred);
                    if (lane == 0) M[((size_t)(cls * CAP + r)) * 8 + W] = bits;
                }
            });
        }
    }
    __threadfence();
    if (lane == 0)
        __hip_atomic_fetch_add(&ctrl[cls], 1u, __ATOMIC_RELEASE, __HIP_MEMORY_SCOPE_AGENT);

    if (((b & 3) != 0) || (wave != 0)) return;

    // ================= SCAN (wave 0 of blocks 0,4,8,12,16) =================
    if (lane == 0) { while (aload_acq(&ctrl[cls]) < 32u) {} }

    {   // stage matrix rows to LDS
        const ulonglong2* Mg = (const ulonglong2*)(M + (size_t)cls * CAP * 8);
        ulonglong2* Ml = (ulonglong2*)s_mtx;
        for (int it = lane; it < CAP * 4; it += 64) Ml[it] = Mg[it];
    }
    for (int rr = lane; rr < myn; rr += 64) {
        const int g = s_list[rr];
        const float* p = x + g * 6;
        const float b0 = p[0], b1 = p[1], b2 = p[2], b3 = p[3], sc = p[4];
        s_det[rr][0] = b0; s_det[rr][1] = b1; s_det[rr][2] = b2; s_det[rr][3] = b3;
        s_det[rr][4] = sc; s_det[rr][5] = (b2 - b0) * (b3 - b1);
        ((int*)s_det[rr])[6] = g;
    }
    s_ab[lane] = 0;   // shared alive image

    // scan state: lane L owns clean clusters 8L..8L+7; dirty clusters in s_dov rows
    u32 aliveB = 0;
    int dirtyCnt = 0;
    bool consA = false;
    int resCode = 0, resIdx = 0;

    auto resolve = [&](int r) {
        const float bx0 = s_det[r][0], bx1 = s_det[r][1];
        const float bx2 = s_det[r][2], bx3 = s_det[r][3];
        const float sc = s_det[r][4], a1 = s_det[r][5];
        const u32 rowByte = (u32)s_mtx[(size_t)r * 64 + lane];
        const u32 mC = rowByte & aliveB;
        const u64 balC = __ballot(mC != 0u);
        int rank_c = INF;
        if (balC) {
            const int wl = (int)__builtin_ctzll(balC);
            const u32 byte = (u32)__builtin_amdgcn_readlane((int)mC, wl);
            rank_c = wl * 8 + (int)__builtin_ctz(byte);
        }
        int rank_d = INF, di = -1;
        if (dirtyCnt > 0) {
            bool p = false; int myrk = INF;
            if (lane < dirtyCnt) {
                const float* dv = s_dov[lane];
                p = iou_pred(bx0, bx1, bx2, bx3, a1, dv[0], dv[1], dv[2], dv[3], dv[4]);
                myrk = ((const int*)dv)[10];
            }
            u64 mk = __ballot(p);
            while (mk) {
                const int l = (int)__builtin_ctzll(mk);
                mk &= mk - 1;
                const int rk = __builtin_amdgcn_readlane(myrk, l);
                if (rk < rank_d) { rank_d = rk; di = l; }
            }
            for (int dd = 64; dd < dirtyCnt; ++dd) {
                const float* dv = s_dov[dd];
                if (iou_pred(bx0, bx1, bx2, bx3, a1, dv[0], dv[1], dv[2], dv[3], dv[4])) {
                    const int rk = ((const int*)dv)[10];
                    if (rk < rank_d) { rank_d = rk; di = dd; }
                }
            }
        }
        if (rank_c == INF && rank_d == INF) {
            aliveB |= ((r >> 3) == lane) ? (1u << (r & 7)) : 0u;
            resCode = 0;
        } else if (rank_c < rank_d) {
            const int rc = rank_c;
            aliveB &= ~(((rc >> 3) == lane) ? (1u << (rc & 7)) : 0u);
            const float cb0 = s_det[rc][0], cb1 = s_det[rc][1];
            const float cb2 = s_det[rc][2], cb3 = s_det[rc][3];
            const float csc = s_det[rc][4];
            const int cgi = ((const int*)s_det[rc])[6];
            const float ns0 = (csc * cb0) + sc * bx0;
            const float ns1 = (csc * cb1) + sc * bx1;
            const float ns2 = (csc * cb2) + sc * bx2;
            const float ns3 = (csc * cb3) + sc * bx3;
            const float nss = csc + sc;
            const float nm0 = ns0 / nss, nm1 = ns1 / nss;
            const float nm2 = ns2 / nss, nm3 = ns3 / nss;
            const int D = dirtyCnt;
            if (lane == 0 && D < 128) {
                float* dv = s_dov[D];
                dv[0] = nm0; dv[1] = nm1; dv[2] = nm2; dv[3] = nm3;
                dv[4] = (nm2 - nm0) * (nm3 - nm1);
                dv[5] = ns0; dv[6] = ns1; dv[7] = ns2; dv[8] = ns3; dv[9] = nss;
                ((int*)dv)[10] = rc; ((int*)dv)[11] = cgi; ((int*)dv)[12] = 2;
            }
            dirtyCnt++;
            resCode = 1; resIdx = D;
        } else {
            const float* dv = s_dov[di];
            const float f0 = dv[5] + sc * bx0, f1 = dv[6] + sc * bx1;
            const float f2 = dv[7] + sc * bx2, f3 = dv[8] + sc * bx3;
            const float fs = dv[9] + sc;
            const float nm0 = f0 / fs, nm1 = f1 / fs, nm2 = f2 / fs, nm3 = f3 / fs;
            const int nct = ((const int*)dv)[12] + 1;
            if (lane == 0) {
                float* dw = s_dov[di];
                dw[0] = nm0; dw[1] = nm1; dw[2] = nm2; dw[3] = nm3;
                dw[4] = (nm2 - nm0) * (nm3 - nm1);
                dw[5] = f0; dw[6] = f1; dw[7] = f2; dw[8] = f3; dw[9] = fs;
                ((int*)dw)[12] = nct;
            }
            resCode = 2; resIdx = di;
        }
    };

    // ---- batched scan: 64-det chunks, runs of guaranteed-creates skipped ----
    unrollN<8>([&](auto k_) {
        constexpr int K = decltype(k_)::v;
        const int r0 = K * 64;
        if (r0 < myn) {
            const int cnt = (myn - r0 < 64) ? (myn - r0) : 64;
            const bool valid = lane < cnt;
            const u64 validM = (cnt == 64) ? ~0ull : (((u64)1 << cnt) - 1ull);
            // tightened rowNE: prior-chunk words masked by current alive image;
            // own-chunk word unmasked (intra-chunk creates); words > K are zero.
            u64 orv = 0ull;
            {
                const int rr = r0 + (valid ? lane : 0);
                const u64* rp = (const u64*)&s_mtx[(size_t)rr * 64];
                const u64* av = (const u64*)s_ab;
                unrollN<8>([&](auto w_) {
                    constexpr int W = decltype(w_)::v;
                    if (W < K)       orv |= rp[W] & av[W];
                    else if (W == K) orv |= rp[W];
                });
            }
            const u64 rowW = __ballot(valid && orv != 0ull);
            float4 db = make_float4(0.f, 0.f, 0.f, 0.f);
            float2 de = make_float2(1.f, 0.f);
            if (valid) {
                db = *(const float4*)&s_det[r0 + lane][0];
                de = *(const float2*)&s_det[r0 + lane][4];
            }
            // dirty-match mask: bit d = my det matches dirty cluster d (exact)
            u64 dmask = 0ull;
            if (!consA) {
                const int DN = (dirtyCnt < 64) ? dirtyCnt : 64;
                for (int d = 0; d < DN; ++d) {
                    const float* dv = s_dov[d];
                    const bool pp = valid && iou_pred(db.x, db.y, db.z, db.w, de.y,
                                                     dv[0], dv[1], dv[2], dv[3], dv[4]);
                    if (pp) dmask |= 1ull << d;
                }
            }
            u64 danyb = __ballot(dmask != 0ull);
            int p = 0;
            while (p < cnt) {
                // violation mask: pure scalar ops (no ballot on the chain)
                u64 vm = consA ? validM : ((danyb | rowW) & validM);
                vm &= ~(((u64)1 << p) - 1ull);
                const int F = vm ? (int)__builtin_ctzll(vm) : cnt;
                {   // commit creates [r0+p, r0+F): one masked OR per lane
                    const int lo = r0 + p, h2 = r0 + F;
                    int s = lo - 8 * lane; s = (s > 0) ? s : 0;
                    int e = h2 - 8 * lane; e = (e < 8) ? e : 8;
                    if (e > s) aliveB |= ((0xFFu >> (8 - (e - s))) << s);
                }
                s_ab[lane] = (u8)aliveB;   // keep shared alive image current
                if (F >= cnt) break;
                const int r = r0 + F;
                const u32 rowByte = (u32)s_mtx[(size_t)r * 64 + lane];
                const u64 balC = __ballot((rowByte & aliveB) != 0u);
                const bool Fdirty = consA || (((danyb >> F) & 1ull) != 0ull);
                if (!Fdirty && balC == 0ull) {
                    aliveB |= ((r >> 3) == lane) ? (1u << (r & 7)) : 0u;   // create
                    s_ab[lane] = (u8)aliveB;
                } else {
                    resolve(r);
                    s_ab[lane] = (u8)aliveB;
                    if (resCode != 0) {
                        const int idx = resIdx;
                        if (idx < 64) {
                            const float* dv = s_dov[idx];
                            const bool pnew = valid && (lane > F) &&
                                iou_pred(db.x, db.y, db.z, db.w, de.y,
                                         dv[0], dv[1], dv[2], dv[3], dv[4]);
                            const u64 nb = __ballot(pnew);
                            dmask = (dmask & ~(1ull << idx)) | (((nb >> lane) & 1ull) << idx);
                            danyb = __ballot(dmask != 0ull);
                        } else {
                            consA = true;   // beyond mask capacity: exact-serial rest
                        }
                    }
                }
                p = F + 1;
            }
        }
    });

    // ---- emit compacted records: clean (solo mean, score=sc) then dirty ----
    int wo = 0;
    for (int Kw = 0; Kw < 8; ++Kw) {
        u64 am = 0ull;
        #pragma unroll
        for (int bb = 0; bb < 8; ++bb)
            am |= (u64)(u32)(u8)__builtin_amdgcn_readlane((int)aliveB, Kw * 8 + bb) << (8 * bb);
        const int j = Kw * 64 + lane;
        const bool pred = (am >> lane) & 1ull;
        if (pred) {
            const int pos = wo + (int)__popcll(am & (((u64)1 << lane) - 1));
            const float b0 = s_det[j][0], b1 = s_det[j][1];
            const float b2 = s_det[j][2], b3 = s_det[j][3];
            const float sc = s_det[j][4];
            const int g = ((const int*)s_det[j])[6];
            float* rec = recs + (size_t)(cls * CAP + pos) * 8;
            rec[0] = (sc * b0) / sc; rec[1] = (sc * b1) / sc;
            rec[2] = (sc * b2) / sc; rec[3] = (sc * b3) / sc;
            rec[4] = sc;
            ((int*)rec)[5] = g;
        }
        wo += (int)__popcll(am);
    }
    const int demit = (dirtyCnt < 128) ? dirtyCnt : 128;
    for (int d = lane; d < demit; d += 64) {
        const float* dv = s_dov[d];
        float* rec = recs + (size_t)(cls * CAP + wo + d) * 8;
        rec[0] = dv[0]; rec[1] = dv[1]; rec[2] = dv[2]; rec[3] = dv[3];
        rec[4] = dv[9] / (float)(((const int*)dv)[12]);   // exact IEEE div
        ((int*)rec)[5] = ((const int*)dv)[11];
    }
    if (lane == 0) cnts[cls] = wo + demit;
    __threadfence();
    if (lane == 0)
        __hip_atomic_fetch_add(&ctrl[16], 1u, __ATOMIC_RELEASE, __HIP_MEMORY_SCOPE_AGENT);
}

extern "C" void kernel_launch(void* const* d_in, const int* in_sizes, int n_in,
                              void* d_out, int out_size, void* d_ws, size_t ws_size,
                              hipStream_t stream) {
    const float* x = (const float*)d_in[0];
    float* out = (float*)d_out;
    // ws layout: M 160 KB | ctrl 256 B | cnts 256 B | recs 80 KB
    u64* M      = (u64*)d_ws;
    u32* ctrl   = (u32*)((char*)d_ws + (size_t)NCLS * CAP * 8 * 8);
    int* cnts   = (int*)((char*)d_ws + (size_t)NCLS * CAP * 8 * 8 + 256);
    float* recs = (float*)((char*)d_ws + (size_t)NCLS * CAP * 8 * 8 + 512);
    wbf_all<<<NBLK, 512, 0, stream>>>(x, M, ctrl, recs, cnts, out);
}